// Round 5
// baseline (771.189 us; speedup 1.0000x reference)
//
#include <hip/hip_runtime.h>
#include <stdint.h>

namespace {

constexpr int Bn = 8;
constexpr int Sn = 2048;
constexpr int Cn = 1024;
constexpr int Mn = Bn * Sn;  // 16384
constexpr int NT = 48;       // virtual K-tiles (3 segs x 16) of BK=64
constexpr int NI = NT / 2;

typedef float f32x4 __attribute__((ext_vector_type(4)));
typedef __bf16 bf16x8 __attribute__((ext_vector_type(8)));
typedef unsigned short us8 __attribute__((ext_vector_type(8)));

__device__ __forceinline__ unsigned short f2bf(float f) {
  uint32_t x = __float_as_uint(f);
  x += 0x7fffu + ((x >> 16) & 1u);  // round-to-nearest-even
  return (unsigned short)(x >> 16);
}
__device__ __forceinline__ float bf2f(unsigned short u) {
  return __uint_as_float(((uint32_t)u) << 16);
}

__device__ __forceinline__ void stage16(const unsigned short* g, unsigned short* l) {
  __builtin_amdgcn_global_load_lds(
      (const __attribute__((address_space(1))) void*)g,
      (__attribute__((address_space(3))) void*)l, 16, 0, 0);
}

// f32 -> (hi bf16, lo bf16) split, vectorized
__global__ __launch_bounds__(256) void k_split(const float* __restrict__ src,
                                               unsigned short* __restrict__ hi,
                                               unsigned short* __restrict__ lo, int n) {
  int stride = gridDim.x * blockDim.x;
  for (int i = blockIdx.x * blockDim.x + threadIdx.x; i * 4 < n; i += stride) {
    int j = i * 4;
    float4 v = *(const float4*)(src + j);
    ushort4 h, l;
    h.x = f2bf(v.x); l.x = f2bf(v.x - bf2f(h.x));
    h.y = f2bf(v.y); l.y = f2bf(v.y - bf2f(h.y));
    h.z = f2bf(v.z); l.z = f2bf(v.z - bf2f(h.z));
    h.w = f2bf(v.w); l.w = f2bf(v.w - bf2f(h.w));
    *(ushort4*)(hi + j) = h;
    *(ushort4*)(lo + j) = l;
  }
}

__global__ __launch_bounds__(256) void k_bias2(const float* __restrict__ a,
                                               const float* __restrict__ b,
                                               float* __restrict__ dst) {
  int t = threadIdx.x + blockIdx.x * 256;
  if (t < Cn) { dst[t] = a[t]; dst[Cn + t] = b[t]; }
}

// ---------------------------------------------------------------------------
// 8-phase 256x256 split-bf16 GEMM (T1+T3+T4+T5), virtual K = 3*1024.
// MODE 0: merged QK-projection. A = [x1h|x2h] (hi) / [x1l|x2l] (lo), virtual
//         M=32768; B = weights (side = tM>=Mn selects Wk); C: q rows ->
//         hi/lo interleaved per batch into O0 (d_out), k rows -> O1/O2.
// MODE 1: QK^T per batch. A = q (d_out interleaved), B = kh/kl, C = fp32 S.
// Schedule: 2 K-tiles/iter, 8 phases; regions = (buf, A/B, k-half) 256x32
// each (16 KiB); stages at phases 0/2/4/6 into just-freed regions; counted
// s_waitcnt vmcnt(4) at phases 3 and 7 only (never 0 in the loop).
// ---------------------------------------------------------------------------
template <int MODE>
__global__ __launch_bounds__(512, 2) void gemm8(
    const unsigned short* __restrict__ Ah, const unsigned short* __restrict__ Al,
    const unsigned short* __restrict__ Bh, const unsigned short* __restrict__ Bl,
    const float* __restrict__ bias,
    unsigned short* __restrict__ O0, unsigned short* __restrict__ O1,
    unsigned short* __restrict__ O2, float* __restrict__ Sout) {
  __shared__ unsigned short lds[65536];  // 8 regions x 16 KiB = 128 KiB

  const int bid = blockIdx.x;
  const int chunk = bid & 7;      // XCD id (round-robin dispatch)
  const int r = bid >> 3;         // position within this XCD's contiguous span

  int tM, tN, side = 0, zdec = 0;
  const unsigned short *a0, *a1, *b0, *b1;
  if constexpr (MODE == 0) {
    int y = chunk * 16 + (r >> 2);    // 0..127 (XCD-contiguous rows: A ~1x fetch)
    int x = r & 3;
    tM = y * 256; tN = x * 256;
    side = (y >= 64);
    a0 = Ah; a1 = Al;
    b0 = Bh + side * 1048576; b1 = Bl + side * 1048576;
  } else {
    zdec = chunk;                      // batch per XCD
    int ys = r >> 5, x = (r >> 2) & 7, y4 = r & 3;  // 4-row supertiles
    tM = (ys * 4 + y4) * 256; tN = x * 256;
    a0 = Ah + (long long)zdec * 4194304; a1 = a0 + 2097152;
    b0 = Bh + (long long)zdec * 2097152; b1 = Bl + (long long)zdec * 2097152;
  }

  const int tid = threadIdx.x;
  const int l = tid & 63;
  const int w = tid >> 6;
  const int wm = w >> 2, wn = w & 3;   // 2 x 4 wave grid
  const int lr = l & 15;
  const int lk = l >> 4;

  // stage one 256x32 region (16 KiB): 2 x global_load_lds(16B) per thread.
  // region ids: buf*4 + {0:A-k0, 1:A-k1, 2:B-k0, 3:B-k1}
  auto stg = [&](int region, int tile, int ks, bool isA) {
    int tt = tile < NT ? tile : NT - 1;       // tail clamp keeps vmcnt ledger uniform
    int seg = tt >> 4;
    int k0 = (tt & 15) * 64 + ks * 32;
    const unsigned short* G = isA ? (seg == 2 ? a1 : a0) : (seg == 1 ? b1 : b0);
    int tb = isA ? tM : tN;
    unsigned short* D = lds + region * 8192;
#pragma unroll
    for (int j = 0; j < 2; ++j)
      stage16(G + (long long)(tb + j * 128 + (tid >> 2)) * 1024 + k0 + (tid & 3) * 8,
              D + j * 4096 + (size_t)tid * 8);
  };

  f32x4 acc[8][4] = {};

  // prologue: tile0 (both k-halves) + tile1 k-half0; first 8 loads must land.
  stg(0, 0, 0, true);  stg(2, 0, 0, false);
  stg(1, 0, 1, true);  stg(3, 0, 1, false);
  stg(4, 1, 0, true);  stg(6, 1, 0, false);
  asm volatile("s_waitcnt vmcnt(4)" ::: "memory");
  __builtin_amdgcn_sched_barrier(0);
  __builtin_amdgcn_s_barrier();

  for (int i = 0; i < NI; ++i) {
    const int e = 2 * i;
#pragma unroll
    for (int p = 0; p < 8; ++p) {
      const int buf = p >> 2, q = p & 3, mh = q & 1, ks = q >> 1;
      const unsigned short* Ar = lds + (buf * 4 + ks) * 8192;
      const unsigned short* Br = lds + (buf * 4 + 2 + ks) * 8192;
      bf16x8 av[4], bv[4];
#pragma unroll
      for (int fm = 0; fm < 4; ++fm)
        av[fm] = *(const bf16x8*)&Ar[(wm * 128 + mh * 64 + fm * 16 + lr) * 32 + lk * 8];
#pragma unroll
      for (int fn = 0; fn < 4; ++fn)
        bv[fn] = *(const bf16x8*)&Br[(wn * 64 + fn * 16 + lr) * 32 + lk * 8];
      // stage slots: each targets regions whose reads completed last phase
      if (p == 0)      { stg(5, e + 1, 1, true); stg(7, e + 1, 1, false); }
      else if (p == 2) { stg(0, e + 2, 0, true); stg(2, e + 2, 0, false); }
      else if (p == 4) { stg(1, e + 2, 1, true); stg(3, e + 2, 1, false); }
      else if (p == 6) { stg(4, e + 3, 0, true); stg(6, e + 3, 0, false); }
      __builtin_amdgcn_s_barrier();
      asm volatile("s_waitcnt lgkmcnt(0)" ::: "memory");
      __builtin_amdgcn_sched_barrier(0);
      __builtin_amdgcn_s_setprio(1);
#pragma unroll
      for (int fm = 0; fm < 4; ++fm)
#pragma unroll
        for (int fn = 0; fn < 4; ++fn)
          acc[mh * 4 + fm][fn] = __builtin_amdgcn_mfma_f32_16x16x32_bf16(
              av[fm], bv[fn], acc[mh * 4 + fm][fn], 0, 0, 0);
      __builtin_amdgcn_s_setprio(0);
      if (p == 3 || p == 7) {
        asm volatile("s_waitcnt vmcnt(4)" ::: "memory");
        __builtin_amdgcn_sched_barrier(0);
      }
      __builtin_amdgcn_s_barrier();
    }
  }

#pragma unroll
  for (int am = 0; am < 8; ++am)
#pragma unroll
    for (int an = 0; an < 4; ++an)
#pragma unroll
      for (int r2 = 0; r2 < 4; ++r2) {
        int rg = tM + wm * 128 + am * 16 + (l >> 4) * 4 + r2;
        int cg = tN + wn * 64 + an * 16 + lr;
        float v = acc[am][an][r2];
        if constexpr (MODE == 0) {
          v += bias[side * 1024 + cg];
          unsigned short h = f2bf(v);
          unsigned short lo = f2bf(v - bf2f(h));
          if (!side) {
            long long off = (long long)(rg >> 11) * 4194304ll +
                            (long long)(rg & 2047) * 1024 + cg;
            O0[off] = h;
            O0[off + 2097152ll] = lo;
          } else {
            long long off = (long long)(rg - Mn) * 1024 + cg;
            O1[off] = h;
            O2[off] = lo;
          }
        } else {
          Sout[(long long)zdec * 4194304ll + (long long)rg * 2048 + cg] = v;
        }
      }
}

// ---------------------------------------------------------------------------
// old 128x128 m97-structure GEMM, kept for Vproj (fp32 reg-staged) and PV.
// SRC: 0 = bf16 (global_load_lds), 3 = fp32 -> bf16 hi (reg stage).
// BIAS: 0 none, 2 per-row.  OUTM: 0 f32, 1 bf16.
// ---------------------------------------------------------------------------
template <int SRC>
__device__ __forceinline__ void stage_side(const void* G0, long long goff, int ld,
                                           int k0, int tbase, int t,
                                           unsigned short* Ls) {
#pragma unroll
  for (int c = 0; c < 2; ++c) {
    int idx = c * 256 + t;
    int row = idx >> 2;
    int co = (idx & 3) * 8;
    long long off = goff + (long long)(tbase + row) * ld + k0 + co;
    if constexpr (SRC == 0) {
      stage16((const unsigned short*)G0 + off, Ls + idx * 8);
    } else {
      const float* g = (const float*)G0 + off;
      float4 u0 = *(const float4*)g;
      float4 u1 = *(const float4*)(g + 4);
      float f[8] = {u0.x, u0.y, u0.z, u0.w, u1.x, u1.y, u1.z, u1.w};
      us8 h;
#pragma unroll
      for (int j = 0; j < 8; ++j) h[j] = f2bf(f[j]);
      *(us8*)&Ls[idx * 8] = h;
    }
  }
}

template <int ASRC, int BSRC, int BIAS, int OUTM>
__global__ __launch_bounds__(256) void gemm(
    const void* __restrict__ A0, const void* __restrict__ B0,
    const float* __restrict__ bias, void* __restrict__ C0,
    int K, int lda, int ldb, int ldc,
    long long sAz, long long sBz, long long sCz) {
  __shared__ unsigned short smem[8192];
  unsigned short* As = smem;
  unsigned short* Bs = smem + 4096;

  const int z = blockIdx.z;
  const long long aoff = (long long)z * sAz;
  const long long boff = (long long)z * sBz;
  const long long coff = (long long)z * sCz;
  const int tN = blockIdx.x * 128;
  const int tM = blockIdx.y * 128;
  const int t = threadIdx.x;
  const int l = t & 63;
  const int w = t >> 6;
  const int wr = w >> 1, wc = w & 1;
  const int lr = l & 15;
  const int lk = (l >> 4) * 8;

  f32x4 acc[4][4] = {};

  for (int k0 = 0; k0 < K; k0 += 32) {
    stage_side<ASRC>(A0, aoff, lda, k0, tM, t, As);
    stage_side<BSRC>(B0, boff, ldb, k0, tN, t, Bs);
    __syncthreads();
    bf16x8 a0[4], b0[4];
#pragma unroll
    for (int i = 0; i < 4; ++i) {
      a0[i] = *(const bf16x8*)&As[(wr * 64 + i * 16 + lr) * 32 + lk];
      b0[i] = *(const bf16x8*)&Bs[(wc * 64 + i * 16 + lr) * 32 + lk];
    }
#pragma unroll
    for (int mi = 0; mi < 4; ++mi)
#pragma unroll
      for (int ni = 0; ni < 4; ++ni)
        acc[mi][ni] = __builtin_amdgcn_mfma_f32_16x16x32_bf16(a0[mi], b0[ni], acc[mi][ni], 0, 0, 0);
    __syncthreads();
  }

#pragma unroll
  for (int mi = 0; mi < 4; ++mi)
#pragma unroll
    for (int ni = 0; ni < 4; ++ni)
#pragma unroll
      for (int r = 0; r < 4; ++r) {
        int rg = tM + wr * 64 + mi * 16 + (l >> 4) * 4 + r;
        int cg = tN + wc * 64 + ni * 16 + lr;
        float v = acc[mi][ni][r];
        if constexpr (BIAS == 2) v += bias[rg];
        long long off = coff + (long long)rg * ldc + cg;
        if constexpr (OUTM == 0) ((float*)C0)[off] = v;
        else ((unsigned short*)C0)[off] = f2bf(v);
      }
}

// In-place row softmax: fp32 row [Sn] -> normalized bf16 attn in first Sn shorts.
__global__ __launch_bounds__(256) void k_softmax(float* __restrict__ S) {
  const long long row = blockIdx.x;
  float* src = S + row * Sn;
  const int t = threadIdx.x;
  float4 v0 = *(const float4*)(src + t * 8);
  float4 v1 = *(const float4*)(src + t * 8 + 4);
  float m = fmaxf(fmaxf(fmaxf(v0.x, v0.y), fmaxf(v0.z, v0.w)),
                  fmaxf(fmaxf(v1.x, v1.y), fmaxf(v1.z, v1.w)));
#pragma unroll
  for (int off = 32; off > 0; off >>= 1) m = fmaxf(m, __shfl_xor(m, off));
  __shared__ float red[8];
  if ((t & 63) == 0) red[t >> 6] = m;
  __syncthreads();
  m = fmaxf(fmaxf(red[0], red[1]), fmaxf(red[2], red[3]));
  float e[8];
  e[0] = __expf(v0.x - m); e[1] = __expf(v0.y - m);
  e[2] = __expf(v0.z - m); e[3] = __expf(v0.w - m);
  e[4] = __expf(v1.x - m); e[5] = __expf(v1.y - m);
  e[6] = __expf(v1.z - m); e[7] = __expf(v1.w - m);
  float s = ((e[0] + e[1]) + (e[2] + e[3])) + ((e[4] + e[5]) + (e[6] + e[7]));
#pragma unroll
  for (int off = 32; off > 0; off >>= 1) s += __shfl_xor(s, off);
  if ((t & 63) == 0) red[4 + (t >> 6)] = s;
  __syncthreads();
  s = (red[4] + red[5]) + (red[6] + red[7]);
  float inv = 1.0f / s;
  us8 o;
#pragma unroll
  for (int j = 0; j < 8; ++j) o[j] = f2bf(e[j] * inv);
  *(us8*)((unsigned short*)src + t * 8) = o;
}

}  // namespace

extern "C" void kernel_launch(void* const* d_in, const int* in_sizes, int n_in,
                              void* d_out, int out_size, void* d_ws, size_t ws_size,
                              hipStream_t stream) {
  (void)in_sizes; (void)n_in; (void)out_size;
  const float* x1 = (const float*)d_in[0];
  const float* x2 = (const float*)d_in[1];
  const float* x3 = (const float*)d_in[2];
  const float* Wq = (const float*)d_in[3];
  const float* bq = (const float*)d_in[4];
  const float* Wk = (const float*)d_in[5];
  const float* bk = (const float*)d_in[6];
  const float* Wv = (const float*)d_in[7];
  const float* bv = (const float*)d_in[8];
  float* out = (float*)d_out;
  char* ws = (char*)d_ws;

  const size_t MiB = 1048576ull;
  // ws layout (MiB): [0,4) w-hi (Wq|Wk) [4,8) w-lo [8,~) bias_cat
  // [12,44) x1h [44,76) x2h (contig virt A-hi) [76,108) x1l [108,140) x2l
  // [140,172) kh [172,204) kl [204,236) vT ; S fp32 overlays [12,140)
  unsigned short* wqh = (unsigned short*)(ws);
  unsigned short* wql = (unsigned short*)(ws + 4 * MiB);
  float* bias_cat = (float*)(ws + 8 * MiB);
  unsigned short* x1h = (unsigned short*)(ws + 12 * MiB);
  unsigned short* x2h = (unsigned short*)(ws + 44 * MiB);
  unsigned short* x1l = (unsigned short*)(ws + 76 * MiB);
  unsigned short* x2l = (unsigned short*)(ws + 108 * MiB);
  unsigned short* kh  = (unsigned short*)(ws + 140 * MiB);
  unsigned short* kl  = (unsigned short*)(ws + 172 * MiB);
  unsigned short* vT  = (unsigned short*)(ws + 204 * MiB);
  float* S = (float*)(ws + 12 * MiB);
  if (ws_size < 236 * MiB) return;  // visible failure => ws probe

  unsigned short* qh = (unsigned short*)d_out;  // q hi/lo interleaved per batch

  const int nx = Mn * Cn, nw = Cn * Cn;
  k_split<<<2048, 256, 0, stream>>>(x1, x1h, x1l, nx);
  k_split<<<2048, 256, 0, stream>>>(x2, x2h, x2l, nx);
  k_split<<<256, 256, 0, stream>>>(Wq, wqh, wql, nw);
  k_split<<<256, 256, 0, stream>>>(Wk, wqh + 1048576, wql + 1048576, nw);
  k_bias2<<<4, 256, 0, stream>>>(bq, bk, bias_cat);

  // merged Q+K projection, 8-phase 256^2 (virtual M=32768)
  gemm8<0><<<512, 512, 0, stream>>>(x1h, x1l, wqh, wql, bias_cat,
                                    qh, kh, kl, nullptr);
  // vT[d][s] = (x3 @ Wv^T + bv)^T : A=Wv (fp32 reg-staged), B^T=x3, row bias
  dim3 gv(Mn / 128, Cn / 128, 1);
  gemm<3, 3, 2, 1><<<gv, 256, 0, stream>>>(Wv, x3, bv, vT, Cn, Cn, Cn, Mn, 0, 0, 0);
  // scores[b] = q[b] @ k[b]^T, 8-phase 256^2 per batch (NO 1/sqrt(d))
  gemm8<1><<<512, 512, 0, stream>>>(qh, nullptr, kh, kl, nullptr,
                                    nullptr, nullptr, nullptr, S);
  // in-place softmax -> bf16 attn rows
  k_softmax<<<Mn, 256, 0, stream>>>(S);
  // out[b] = attn[b] @ v[b] : A=attn (bf16, lda 2*Sn), B^T=vT cols b*Sn..
  dim3 gp(Cn / 128, Sn / 128, Bn);
  gemm<0, 0, 0, 0><<<gp, 256, 0, stream>>>(
      (unsigned short*)S, vT, nullptr, out,
      Sn, 2 * Sn, Mn, Cn,
      (long long)Sn * Sn * 2, (long long)Sn, (long long)Sn * Cn);
}

// Round 6
// 741.163 us; speedup vs baseline: 1.0405x; 1.0405x over previous
//
#include <hip/hip_runtime.h>
#include <stdint.h>

namespace {

constexpr int Bn = 8;
constexpr int Sn = 2048;
constexpr int Cn = 1024;
constexpr int Mn = Bn * Sn;  // 16384
constexpr int NT = 48;       // virtual K-tiles (3 segs x 16) of BK=64
constexpr int NI = NT / 2;

typedef float f32x4 __attribute__((ext_vector_type(4)));
typedef __bf16 bf16x8 __attribute__((ext_vector_type(8)));
typedef unsigned short us8 __attribute__((ext_vector_type(8)));

__device__ __forceinline__ unsigned short f2bf(float f) {
  uint32_t x = __float_as_uint(f);
  x += 0x7fffu + ((x >> 16) & 1u);  // round-to-nearest-even
  return (unsigned short)(x >> 16);
}
__device__ __forceinline__ float bf2f(unsigned short u) {
  return __uint_as_float(((uint32_t)u) << 16);
}

__device__ __forceinline__ void stage16(const unsigned short* g, unsigned short* l) {
  __builtin_amdgcn_global_load_lds(
      (const __attribute__((address_space(1))) void*)g,
      (__attribute__((address_space(3))) void*)l, 16, 0, 0);
}

// f32 -> (hi bf16, lo bf16) split, vectorized
__global__ __launch_bounds__(256) void k_split(const float* __restrict__ src,
                                               unsigned short* __restrict__ hi,
                                               unsigned short* __restrict__ lo, int n) {
  int stride = gridDim.x * blockDim.x;
  for (int i = blockIdx.x * blockDim.x + threadIdx.x; i * 4 < n; i += stride) {
    int j = i * 4;
    float4 v = *(const float4*)(src + j);
    ushort4 h, l;
    h.x = f2bf(v.x); l.x = f2bf(v.x - bf2f(h.x));
    h.y = f2bf(v.y); l.y = f2bf(v.y - bf2f(h.y));
    h.z = f2bf(v.z); l.z = f2bf(v.z - bf2f(h.z));
    h.w = f2bf(v.w); l.w = f2bf(v.w - bf2f(h.w));
    *(ushort4*)(hi + j) = h;
    *(ushort4*)(lo + j) = l;
  }
}

__global__ __launch_bounds__(256) void k_bias2(const float* __restrict__ a,
                                               const float* __restrict__ b,
                                               float* __restrict__ dst) {
  int t = threadIdx.x + blockIdx.x * 256;
  if (t < Cn) { dst[t] = a[t]; dst[Cn + t] = b[t]; }
}

// ---------------------------------------------------------------------------
// 8-phase 256x256 split-bf16 GEMM (T1+T2+T3+T4+T5), virtual K = 3*1024.
// MODE 0: merged QK-projection (virtual M=32768; side=tM>=Mn selects Wk).
// MODE 1: QK^T per batch (batch = XCD chunk).
// Regions: (buf, A/B, k-half) 256x32 each (16 KiB), row = 64 B.
// T2 swizzle: 16B-slot index XORed with (row>>1)&3; LDS dest stays linear
// (global_load_lds), so the SOURCE column is pre-swizzled with the same
// involution and the read column applies the same XOR (rule #21).
// Counted vmcnt(4) at phases 3/7 only; never drained to 0 in the loop.
// ---------------------------------------------------------------------------
template <int MODE>
__global__ __launch_bounds__(512, 2) void gemm8(
    const unsigned short* __restrict__ Ah, const unsigned short* __restrict__ Al,
    const unsigned short* __restrict__ Bh, const unsigned short* __restrict__ Bl,
    const float* __restrict__ bias,
    unsigned short* __restrict__ O0, unsigned short* __restrict__ O1,
    unsigned short* __restrict__ O2, float* __restrict__ Sout) {
  __shared__ unsigned short lds[65536];  // 8 regions x 16 KiB = 128 KiB

  const int bid = blockIdx.x;
  const int chunk = bid & 7;      // XCD id (round-robin dispatch)
  const int r = bid >> 3;         // position within this XCD's contiguous span

  int tM, tN, side = 0, zdec = 0;
  const unsigned short *a0, *a1, *b0, *b1;
  if constexpr (MODE == 0) {
    int y = chunk * 16 + (r >> 2);    // XCD-contiguous rows: A ~1x fetch
    int x = r & 3;
    tM = y * 256; tN = x * 256;
    side = (y >= 64);
    a0 = Ah; a1 = Al;
    b0 = Bh + side * 1048576; b1 = Bl + side * 1048576;
  } else {
    zdec = chunk;                      // batch per XCD
    int ys = r >> 5, x = (r >> 2) & 7, y4 = r & 3;  // 4-row supertiles
    tM = (ys * 4 + y4) * 256; tN = x * 256;
    a0 = Ah + (long long)zdec * 4194304; a1 = a0 + 2097152;
    b0 = Bh + (long long)zdec * 2097152; b1 = Bl + (long long)zdec * 2097152;
  }

  const int tid = threadIdx.x;
  const int l = tid & 63;
  const int w = tid >> 6;
  const int wm = w >> 2, wn = w & 3;   // 2 x 4 wave grid
  const int lr = l & 15;
  const int lk = l >> 4;
  // T2: source-side swizzled slot (involution), read-side XOR (shorts)
  const int ssw = ((tid & 3) ^ ((tid >> 3) & 3)) * 8;
  const int rsw = (lk ^ ((lr >> 1) & 3)) * 8;

  // stage one 256x32 region (16 KiB): 2 x global_load_lds(16B) per thread.
  auto stg = [&](int region, int tile, int ks, bool isA) {
    int tt = tile < NT ? tile : NT - 1;       // tail clamp keeps vmcnt ledger uniform
    int seg = tt >> 4;
    int k0 = (tt & 15) * 64 + ks * 32;
    const unsigned short* G = isA ? (seg == 2 ? a1 : a0) : (seg == 1 ? b1 : b0);
    int tb = isA ? tM : tN;
    unsigned short* D = lds + region * 8192;
#pragma unroll
    for (int j = 0; j < 2; ++j)
      stage16(G + (long long)(tb + j * 128 + (tid >> 2)) * 1024 + k0 + ssw,
              D + j * 4096 + (size_t)tid * 8);
  };

  f32x4 acc[8][4] = {};

  // prologue: tile0 (both k-halves) + tile1 k-half0; first 8 loads must land.
  stg(0, 0, 0, true);  stg(2, 0, 0, false);
  stg(1, 0, 1, true);  stg(3, 0, 1, false);
  stg(4, 1, 0, true);  stg(6, 1, 0, false);
  asm volatile("s_waitcnt vmcnt(4)" ::: "memory");
  __builtin_amdgcn_sched_barrier(0);
  __builtin_amdgcn_s_barrier();

  for (int i = 0; i < NI; ++i) {
    const int e = 2 * i;
#pragma unroll
    for (int p = 0; p < 8; ++p) {
      const int buf = p >> 2, q = p & 3, mh = q & 1, ks = q >> 1;
      const unsigned short* Ar = lds + (buf * 4 + ks) * 8192;
      const unsigned short* Br = lds + (buf * 4 + 2 + ks) * 8192;
      bf16x8 av[4], bv[4];
#pragma unroll
      for (int fm = 0; fm < 4; ++fm)
        av[fm] = *(const bf16x8*)&Ar[(wm * 128 + mh * 64 + fm * 16 + lr) * 32 + rsw];
#pragma unroll
      for (int fn = 0; fn < 4; ++fn)
        bv[fn] = *(const bf16x8*)&Br[(wn * 64 + fn * 16 + lr) * 32 + rsw];
      // stage slots: each targets regions whose reads completed last phase
      if (p == 0)      { stg(5, e + 1, 1, true); stg(7, e + 1, 1, false); }
      else if (p == 2) { stg(0, e + 2, 0, true); stg(2, e + 2, 0, false); }
      else if (p == 4) { stg(1, e + 2, 1, true); stg(3, e + 2, 1, false); }
      else if (p == 6) { stg(4, e + 3, 0, true); stg(6, e + 3, 0, false); }
      __builtin_amdgcn_s_barrier();
      asm volatile("s_waitcnt lgkmcnt(0)" ::: "memory");
      __builtin_amdgcn_sched_barrier(0);
      __builtin_amdgcn_s_setprio(1);
#pragma unroll
      for (int fm = 0; fm < 4; ++fm)
#pragma unroll
        for (int fn = 0; fn < 4; ++fn)
          acc[mh * 4 + fm][fn] = __builtin_amdgcn_mfma_f32_16x16x32_bf16(
              av[fm], bv[fn], acc[mh * 4 + fm][fn], 0, 0, 0);
      __builtin_amdgcn_s_setprio(0);
      if (p == 3 || p == 7) {
        asm volatile("s_waitcnt vmcnt(4)" ::: "memory");
        __builtin_amdgcn_sched_barrier(0);
      }
      __builtin_amdgcn_s_barrier();
    }
  }

#pragma unroll
  for (int am = 0; am < 8; ++am)
#pragma unroll
    for (int an = 0; an < 4; ++an)
#pragma unroll
      for (int r2 = 0; r2 < 4; ++r2) {
        int rg = tM + wm * 128 + am * 16 + (l >> 4) * 4 + r2;
        int cg = tN + wn * 64 + an * 16 + lr;
        float v = acc[am][an][r2];
        if constexpr (MODE == 0) {
          v += bias[side * 1024 + cg];
          unsigned short h = f2bf(v);
          unsigned short lo = f2bf(v - bf2f(h));
          if (!side) {
            long long off = (long long)(rg >> 11) * 4194304ll +
                            (long long)(rg & 2047) * 1024 + cg;
            O0[off] = h;
            O0[off + 2097152ll] = lo;
          } else {
            long long off = (long long)(rg - Mn) * 1024 + cg;
            O1[off] = h;
            O2[off] = lo;
          }
        } else {
          Sout[(long long)zdec * 4194304ll + (long long)rg * 2048 + cg] = v;
        }
      }
}

// ---------------------------------------------------------------------------
// old 128x128 m97-structure GEMM, kept for Vproj (fp32 reg-staged) and PV.
// ---------------------------------------------------------------------------
template <int SRC>
__device__ __forceinline__ void stage_side(const void* G0, long long goff, int ld,
                                           int k0, int tbase, int t,
                                           unsigned short* Ls) {
#pragma unroll
  for (int c = 0; c < 2; ++c) {
    int idx = c * 256 + t;
    int row = idx >> 2;
    int co = (idx & 3) * 8;
    long long off = goff + (long long)(tbase + row) * ld + k0 + co;
    if constexpr (SRC == 0) {
      stage16((const unsigned short*)G0 + off, Ls + idx * 8);
    } else {
      const float* g = (const float*)G0 + off;
      float4 u0 = *(const float4*)g;
      float4 u1 = *(const float4*)(g + 4);
      float f[8] = {u0.x, u0.y, u0.z, u0.w, u1.x, u1.y, u1.z, u1.w};
      us8 h;
#pragma unroll
      for (int j = 0; j < 8; ++j) h[j] = f2bf(f[j]);
      *(us8*)&Ls[idx * 8] = h;
    }
  }
}

template <int ASRC, int BSRC, int BIAS, int OUTM>
__global__ __launch_bounds__(256) void gemm(
    const void* __restrict__ A0, const void* __restrict__ B0,
    const float* __restrict__ bias, void* __restrict__ C0,
    int K, int lda, int ldb, int ldc,
    long long sAz, long long sBz, long long sCz) {
  __shared__ unsigned short smem[8192];
  unsigned short* As = smem;
  unsigned short* Bs = smem + 4096;

  const int z = blockIdx.z;
  const long long aoff = (long long)z * sAz;
  const long long boff = (long long)z * sBz;
  const long long coff = (long long)z * sCz;
  const int tN = blockIdx.x * 128;
  const int tM = blockIdx.y * 128;
  const int t = threadIdx.x;
  const int l = t & 63;
  const int w = t >> 6;
  const int wr = w >> 1, wc = w & 1;
  const int lr = l & 15;
  const int lk = (l >> 4) * 8;

  f32x4 acc[4][4] = {};

  for (int k0 = 0; k0 < K; k0 += 32) {
    stage_side<ASRC>(A0, aoff, lda, k0, tM, t, As);
    stage_side<BSRC>(B0, boff, ldb, k0, tN, t, Bs);
    __syncthreads();
    bf16x8 a0[4], b0[4];
#pragma unroll
    for (int i = 0; i < 4; ++i) {
      a0[i] = *(const bf16x8*)&As[(wr * 64 + i * 16 + lr) * 32 + lk];
      b0[i] = *(const bf16x8*)&Bs[(wc * 64 + i * 16 + lr) * 32 + lk];
    }
#pragma unroll
    for (int mi = 0; mi < 4; ++mi)
#pragma unroll
      for (int ni = 0; ni < 4; ++ni)
        acc[mi][ni] = __builtin_amdgcn_mfma_f32_16x16x32_bf16(a0[mi], b0[ni], acc[mi][ni], 0, 0, 0);
    __syncthreads();
  }

#pragma unroll
  for (int mi = 0; mi < 4; ++mi)
#pragma unroll
    for (int ni = 0; ni < 4; ++ni)
#pragma unroll
      for (int r = 0; r < 4; ++r) {
        int rg = tM + wr * 64 + mi * 16 + (l >> 4) * 4 + r;
        int cg = tN + wc * 64 + ni * 16 + lr;
        float v = acc[mi][ni][r];
        if constexpr (BIAS == 2) v += bias[rg];
        long long off = coff + (long long)rg * ldc + cg;
        if constexpr (OUTM == 0) ((float*)C0)[off] = v;
        else ((unsigned short*)C0)[off] = f2bf(v);
      }
}

// In-place row softmax: fp32 row [Sn] -> normalized bf16 attn in first Sn shorts.
__global__ __launch_bounds__(256) void k_softmax(float* __restrict__ S) {
  const long long row = blockIdx.x;
  float* src = S + row * Sn;
  const int t = threadIdx.x;
  float4 v0 = *(const float4*)(src + t * 8);
  float4 v1 = *(const float4*)(src + t * 8 + 4);
  float m = fmaxf(fmaxf(fmaxf(v0.x, v0.y), fmaxf(v0.z, v0.w)),
                  fmaxf(fmaxf(v1.x, v1.y), fmaxf(v1.z, v1.w)));
#pragma unroll
  for (int off = 32; off > 0; off >>= 1) m = fmaxf(m, __shfl_xor(m, off));
  __shared__ float red[8];
  if ((t & 63) == 0) red[t >> 6] = m;
  __syncthreads();
  m = fmaxf(fmaxf(red[0], red[1]), fmaxf(red[2], red[3]));
  float e[8];
  e[0] = __expf(v0.x - m); e[1] = __expf(v0.y - m);
  e[2] = __expf(v0.z - m); e[3] = __expf(v0.w - m);
  e[4] = __expf(v1.x - m); e[5] = __expf(v1.y - m);
  e[6] = __expf(v1.z - m); e[7] = __expf(v1.w - m);
  float s = ((e[0] + e[1]) + (e[2] + e[3])) + ((e[4] + e[5]) + (e[6] + e[7]));
#pragma unroll
  for (int off = 32; off > 0; off >>= 1) s += __shfl_xor(s, off);
  if ((t & 63) == 0) red[4 + (t >> 6)] = s;
  __syncthreads();
  s = (red[4] + red[5]) + (red[6] + red[7]);
  float inv = 1.0f / s;
  us8 o;
#pragma unroll
  for (int j = 0; j < 8; ++j) o[j] = f2bf(e[j] * inv);
  *(us8*)((unsigned short*)src + t * 8) = o;
}

}  // namespace

extern "C" void kernel_launch(void* const* d_in, const int* in_sizes, int n_in,
                              void* d_out, int out_size, void* d_ws, size_t ws_size,
                              hipStream_t stream) {
  (void)in_sizes; (void)n_in; (void)out_size;
  const float* x1 = (const float*)d_in[0];
  const float* x2 = (const float*)d_in[1];
  const float* x3 = (const float*)d_in[2];
  const float* Wq = (const float*)d_in[3];
  const float* bq = (const float*)d_in[4];
  const float* Wk = (const float*)d_in[5];
  const float* bk = (const float*)d_in[6];
  const float* Wv = (const float*)d_in[7];
  const float* bv = (const float*)d_in[8];
  float* out = (float*)d_out;
  char* ws = (char*)d_ws;

  const size_t MiB = 1048576ull;
  // ws layout (MiB): [0,4) w-hi (Wq|Wk) [4,8) w-lo [8,~) bias_cat
  // [12,44) x1h [44,76) x2h (contig virt A-hi) [76,108) x1l [108,140) x2l
  // [140,172) kh [172,204) kl [204,236) vT ; S fp32 overlays [12,140)
  unsigned short* wqh = (unsigned short*)(ws);
  unsigned short* wql = (unsigned short*)(ws + 4 * MiB);
  float* bias_cat = (float*)(ws + 8 * MiB);
  unsigned short* x1h = (unsigned short*)(ws + 12 * MiB);
  unsigned short* x2h = (unsigned short*)(ws + 44 * MiB);
  unsigned short* x1l = (unsigned short*)(ws + 76 * MiB);
  unsigned short* x2l = (unsigned short*)(ws + 108 * MiB);
  unsigned short* kh  = (unsigned short*)(ws + 140 * MiB);
  unsigned short* kl  = (unsigned short*)(ws + 172 * MiB);
  unsigned short* vT  = (unsigned short*)(ws + 204 * MiB);
  float* S = (float*)(ws + 12 * MiB);
  if (ws_size < 236 * MiB) return;  // visible failure => ws probe

  unsigned short* qh = (unsigned short*)d_out;  // q hi/lo interleaved per batch

  const int nx = Mn * Cn, nw = Cn * Cn;
  k_split<<<2048, 256, 0, stream>>>(x1, x1h, x1l, nx);
  k_split<<<2048, 256, 0, stream>>>(x2, x2h, x2l, nx);
  k_split<<<256, 256, 0, stream>>>(Wq, wqh, wql, nw);
  k_split<<<256, 256, 0, stream>>>(Wk, wqh + 1048576, wql + 1048576, nw);
  k_bias2<<<4, 256, 0, stream>>>(bq, bk, bias_cat);

  // merged Q+K projection, 8-phase 256^2 (virtual M=32768)
  gemm8<0><<<512, 512, 0, stream>>>(x1h, x1l, wqh, wql, bias_cat,
                                    qh, kh, kl, nullptr);
  // vT[d][s] = (x3 @ Wv^T + bv)^T : A=Wv (fp32 reg-staged), B^T=x3, row bias
  dim3 gv(Mn / 128, Cn / 128, 1);
  gemm<3, 3, 2, 1><<<gv, 256, 0, stream>>>(Wv, x3, bv, vT, Cn, Cn, Cn, Mn, 0, 0, 0);
  // scores[b] = q[b] @ k[b]^T, 8-phase 256^2 per batch (NO 1/sqrt(d))
  gemm8<1><<<512, 512, 0, stream>>>(qh, nullptr, kh, kl, nullptr,
                                    nullptr, nullptr, nullptr, S);
  // in-place softmax -> bf16 attn rows
  k_softmax<<<Mn, 256, 0, stream>>>(S);
  // out[b] = attn[b] @ v[b] : A=attn (bf16, lda 2*Sn), B^T=vT cols b*Sn..
  dim3 gp(Cn / 128, Sn / 128, Bn);
  gemm<0, 0, 0, 0><<<gp, 256, 0, stream>>>(
      (unsigned short*)S, vT, nullptr, out,
      Sn, 2 * Sn, Mn, Cn,
      (long long)Sn * Sn * 2, (long long)Sn, (long long)Sn * Cn);
}

// Round 7
// 735.433 us; speedup vs baseline: 1.0486x; 1.0078x over previous
//
#include <hip/hip_runtime.h>
#include <stdint.h>

namespace {

constexpr int Bn = 8;
constexpr int Sn = 2048;
constexpr int Cn = 1024;
constexpr int Mn = Bn * Sn;  // 16384
constexpr int NT = 48;       // virtual K-tiles (3 segs x 16) of BK=64
constexpr int NI = NT / 2;

typedef float f32x4 __attribute__((ext_vector_type(4)));
typedef __bf16 bf16x8 __attribute__((ext_vector_type(8)));
typedef unsigned short us8 __attribute__((ext_vector_type(8)));

__device__ __forceinline__ unsigned short f2bf(float f) {
  uint32_t x = __float_as_uint(f);
  x += 0x7fffu + ((x >> 16) & 1u);  // round-to-nearest-even
  return (unsigned short)(x >> 16);
}
__device__ __forceinline__ float bf2f(unsigned short u) {
  return __uint_as_float(((uint32_t)u) << 16);
}

__device__ __forceinline__ void stage16(const unsigned short* g, unsigned short* l) {
  __builtin_amdgcn_global_load_lds(
      (const __attribute__((address_space(1))) void*)g,
      (__attribute__((address_space(3))) void*)l, 16, 0, 0);
}

// f32 -> (hi bf16, lo bf16) split, vectorized
__global__ __launch_bounds__(256) void k_split(const float* __restrict__ src,
                                               unsigned short* __restrict__ hi,
                                               unsigned short* __restrict__ lo, int n) {
  int stride = gridDim.x * blockDim.x;
  for (int i = blockIdx.x * blockDim.x + threadIdx.x; i * 4 < n; i += stride) {
    int j = i * 4;
    float4 v = *(const float4*)(src + j);
    ushort4 h, l;
    h.x = f2bf(v.x); l.x = f2bf(v.x - bf2f(h.x));
    h.y = f2bf(v.y); l.y = f2bf(v.y - bf2f(h.y));
    h.z = f2bf(v.z); l.z = f2bf(v.z - bf2f(h.z));
    h.w = f2bf(v.w); l.w = f2bf(v.w - bf2f(h.w));
    *(ushort4*)(hi + j) = h;
    *(ushort4*)(lo + j) = l;
  }
}

__global__ __launch_bounds__(256) void k_bias2(const float* __restrict__ a,
                                               const float* __restrict__ b,
                                               float* __restrict__ dst) {
  int t = threadIdx.x + blockIdx.x * 256;
  if (t < Cn) { dst[t] = a[t]; dst[Cn + t] = b[t]; }
}

// ---------------------------------------------------------------------------
// 8-phase 256x256 split-bf16 GEMM (T1+T2+T3+T4+T5), virtual K = 3*1024.
// Round-7: one-phase-ahead register prefetch of fragments (double-buffered
// av/bv) + bv reuse across the two mh-phases. Phase j issues ds_reads for
// phase j+1 and MFMAs on fragments read at j-1 behind a COUNTED lgkmcnt.
// Prefetches for p4 / next-p0 sit after the p3/p7 vmcnt(4) (region-validity).
// ---------------------------------------------------------------------------
template <int MODE>
__global__ __launch_bounds__(512, 2) void gemm8(
    const unsigned short* __restrict__ Ah, const unsigned short* __restrict__ Al,
    const unsigned short* __restrict__ Bh, const unsigned short* __restrict__ Bl,
    const float* __restrict__ bias,
    unsigned short* __restrict__ O0, unsigned short* __restrict__ O1,
    unsigned short* __restrict__ O2, float* __restrict__ Sout) {
  __shared__ unsigned short lds[65536];  // 8 regions x 16 KiB = 128 KiB

  const int bid = blockIdx.x;
  const int chunk = bid & 7;      // XCD id (round-robin dispatch)
  const int r = bid >> 3;         // position within this XCD's contiguous span

  int tM, tN, side = 0, zdec = 0;
  const unsigned short *a0, *a1, *b0, *b1;
  if constexpr (MODE == 0) {
    int y = chunk * 16 + (r >> 2);    // XCD-contiguous rows: A ~1x fetch
    int x = r & 3;
    tM = y * 256; tN = x * 256;
    side = (y >= 64);
    a0 = Ah; a1 = Al;
    b0 = Bh + side * 1048576; b1 = Bl + side * 1048576;
  } else {
    zdec = chunk;                      // batch per XCD
    int ys = r >> 5, x = (r >> 2) & 7, y4 = r & 3;  // 4-row supertiles
    tM = (ys * 4 + y4) * 256; tN = x * 256;
    a0 = Ah + (long long)zdec * 4194304; a1 = a0 + 2097152;
    b0 = Bh + (long long)zdec * 2097152; b1 = Bl + (long long)zdec * 2097152;
  }

  const int tid = threadIdx.x;
  const int l = tid & 63;
  const int w = tid >> 6;
  const int wm = w >> 2, wn = w & 3;   // 2 x 4 wave grid
  const int lr = l & 15;
  const int lk = l >> 4;
  // T2: source-side swizzled slot (involution), read-side XOR (shorts)
  const int ssw = ((tid & 3) ^ ((tid >> 3) & 3)) * 8;
  const int rsw = (lk ^ ((lr >> 1) & 3)) * 8;

  // stage one 256x32 region (16 KiB): 2 x global_load_lds(16B) per thread.
  auto stg = [&](int region, int tile, int ks, bool isA) {
    int tt = tile < NT ? tile : NT - 1;       // tail clamp keeps vmcnt ledger uniform
    int seg = tt >> 4;
    int k0 = (tt & 15) * 64 + ks * 32;
    const unsigned short* G = isA ? (seg == 2 ? a1 : a0) : (seg == 1 ? b1 : b0);
    int tb = isA ? tM : tN;
    unsigned short* D = lds + region * 8192;
#pragma unroll
    for (int j = 0; j < 2; ++j)
      stage16(G + (long long)(tb + j * 128 + (tid >> 2)) * 1024 + k0 + ssw,
              D + j * 4096 + (size_t)tid * 8);
  };

  bf16x8 av[2][4], bv[2][4];
  auto rdA = [&](int slot, int buf, int ks, int mh) {
    const unsigned short* Ar = lds + (buf * 4 + ks) * 8192;
#pragma unroll
    for (int fm = 0; fm < 4; ++fm)
      av[slot][fm] = *(const bf16x8*)&Ar[(wm * 128 + mh * 64 + fm * 16 + lr) * 32 + rsw];
  };
  auto rdB = [&](int slot, int buf, int ks) {
    const unsigned short* Br = lds + (buf * 4 + 2 + ks) * 8192;
#pragma unroll
    for (int fn = 0; fn < 4; ++fn)
      bv[slot][fn] = *(const bf16x8*)&Br[(wn * 64 + fn * 16 + lr) * 32 + rsw];
  };

  f32x4 acc[8][4] = {};

  // prologue: tile0 (both k-halves) + tile1 k-half0; regions 0,2,1,3 must land.
  stg(0, 0, 0, true);  stg(2, 0, 0, false);
  stg(1, 0, 1, true);  stg(3, 0, 1, false);
  stg(4, 1, 0, true);  stg(6, 1, 0, false);
  asm volatile("s_waitcnt vmcnt(4)" ::: "memory");
  __builtin_amdgcn_sched_barrier(0);
  __builtin_amdgcn_s_barrier();
  rdA(0, 0, 0, 0);  // fragments for p0
  rdB(0, 0, 0);

  for (int i = 0; i < NI; ++i) {
    const int e = 2 * i;
#pragma unroll
    for (int p = 0; p < 8; ++p) {
      const int q = p & 3, mh = q & 1, ks = q >> 1;
      (void)ks;
      // top: prefetch fragments for phase p+1 (p3/p7 prefetch after vmcnt below)
      if (p != 3 && p != 7) {
        const int pn = p + 1, bufn = pn >> 2, qn = pn & 3;
        rdA(pn & 1, bufn, qn >> 1, qn & 1);
        if ((qn & 1) == 0) rdB((pn >> 1) & 1, bufn, qn >> 1);
      }
      // stage slots: each targets regions whose last reads completed earlier
      if (p == 0)      { stg(5, e + 1, 1, true); stg(7, e + 1, 1, false); }
      else if (p == 2) { stg(0, e + 2, 0, true); stg(2, e + 2, 0, false); }
      else if (p == 4) { stg(1, e + 2, 1, true); stg(3, e + 2, 1, false); }
      else if (p == 6) { stg(4, e + 3, 0, true); stg(6, e + 3, 0, false); }
      __builtin_amdgcn_s_barrier();
      // counted wait: leave only the prefetch reads just issued outstanding
      if (p == 1 || p == 5)      asm volatile("s_waitcnt lgkmcnt(8)" ::: "memory");
      else if (p == 3 || p == 7) asm volatile("s_waitcnt lgkmcnt(0)" ::: "memory");
      else                       asm volatile("s_waitcnt lgkmcnt(4)" ::: "memory");
      __builtin_amdgcn_sched_barrier(0);
      __builtin_amdgcn_s_setprio(1);
#pragma unroll
      for (int fm = 0; fm < 4; ++fm)
#pragma unroll
        for (int fn = 0; fn < 4; ++fn)
          acc[mh * 4 + fm][fn] = __builtin_amdgcn_mfma_f32_16x16x32_bf16(
              av[p & 1][fm], bv[(p >> 1) & 1][fn], acc[mh * 4 + fm][fn], 0, 0, 0);
      __builtin_amdgcn_s_setprio(0);
      if (p == 3 || p == 7) {
        asm volatile("s_waitcnt vmcnt(4)" ::: "memory");
        __builtin_amdgcn_sched_barrier(0);
        const int pn = (p + 1) & 7, bufn = pn >> 2;  // p4 or next-iter p0
        rdA(pn & 1, bufn, 0, 0);
        rdB((pn >> 1) & 1, bufn, 0);
      }
      __builtin_amdgcn_s_barrier();
    }
  }

#pragma unroll
  for (int am = 0; am < 8; ++am)
#pragma unroll
    for (int an = 0; an < 4; ++an)
#pragma unroll
      for (int r2 = 0; r2 < 4; ++r2) {
        int rg = tM + wm * 128 + am * 16 + (l >> 4) * 4 + r2;
        int cg = tN + wn * 64 + an * 16 + lr;
        float v = acc[am][an][r2];
        if constexpr (MODE == 0) {
          v += bias[side * 1024 + cg];
          unsigned short h = f2bf(v);
          unsigned short lo = f2bf(v - bf2f(h));
          if (!side) {
            long long off = (long long)(rg >> 11) * 4194304ll +
                            (long long)(rg & 2047) * 1024 + cg;
            O0[off] = h;
            O0[off + 2097152ll] = lo;
          } else {
            long long off = (long long)(rg - Mn) * 1024 + cg;
            O1[off] = h;
            O2[off] = lo;
          }
        } else {
          Sout[(long long)zdec * 4194304ll + (long long)rg * 2048 + cg] = v;
        }
      }
}

// ---------------------------------------------------------------------------
// old 128x128 m97-structure GEMM, kept for Vproj (fp32 reg-staged) and PV.
// ---------------------------------------------------------------------------
template <int SRC>
__device__ __forceinline__ void stage_side(const void* G0, long long goff, int ld,
                                           int k0, int tbase, int t,
                                           unsigned short* Ls) {
#pragma unroll
  for (int c = 0; c < 2; ++c) {
    int idx = c * 256 + t;
    int row = idx >> 2;
    int co = (idx & 3) * 8;
    long long off = goff + (long long)(tbase + row) * ld + k0 + co;
    if constexpr (SRC == 0) {
      stage16((const unsigned short*)G0 + off, Ls + idx * 8);
    } else {
      const float* g = (const float*)G0 + off;
      float4 u0 = *(const float4*)g;
      float4 u1 = *(const float4*)(g + 4);
      float f[8] = {u0.x, u0.y, u0.z, u0.w, u1.x, u1.y, u1.z, u1.w};
      us8 h;
#pragma unroll
      for (int j = 0; j < 8; ++j) h[j] = f2bf(f[j]);
      *(us8*)&Ls[idx * 8] = h;
    }
  }
}

template <int ASRC, int BSRC, int BIAS, int OUTM>
__global__ __launch_bounds__(256) void gemm(
    const void* __restrict__ A0, const void* __restrict__ B0,
    const float* __restrict__ bias, void* __restrict__ C0,
    int K, int lda, int ldb, int ldc,
    long long sAz, long long sBz, long long sCz) {
  __shared__ unsigned short smem[8192];
  unsigned short* As = smem;
  unsigned short* Bs = smem + 4096;

  const int z = blockIdx.z;
  const long long aoff = (long long)z * sAz;
  const long long boff = (long long)z * sBz;
  const long long coff = (long long)z * sCz;
  const int tN = blockIdx.x * 128;
  const int tM = blockIdx.y * 128;
  const int t = threadIdx.x;
  const int l = t & 63;
  const int w = t >> 6;
  const int wr = w >> 1, wc = w & 1;
  const int lr = l & 15;
  const int lk = (l >> 4) * 8;

  f32x4 acc[4][4] = {};

  for (int k0 = 0; k0 < K; k0 += 32) {
    stage_side<ASRC>(A0, aoff, lda, k0, tM, t, As);
    stage_side<BSRC>(B0, boff, ldb, k0, tN, t, Bs);
    __syncthreads();
    bf16x8 a0[4], b0[4];
#pragma unroll
    for (int i = 0; i < 4; ++i) {
      a0[i] = *(const bf16x8*)&As[(wr * 64 + i * 16 + lr) * 32 + lk];
      b0[i] = *(const bf16x8*)&Bs[(wc * 64 + i * 16 + lr) * 32 + lk];
    }
#pragma unroll
    for (int mi = 0; mi < 4; ++mi)
#pragma unroll
      for (int ni = 0; ni < 4; ++ni)
        acc[mi][ni] = __builtin_amdgcn_mfma_f32_16x16x32_bf16(a0[mi], b0[ni], acc[mi][ni], 0, 0, 0);
    __syncthreads();
  }

#pragma unroll
  for (int mi = 0; mi < 4; ++mi)
#pragma unroll
    for (int ni = 0; ni < 4; ++ni)
#pragma unroll
      for (int r = 0; r < 4; ++r) {
        int rg = tM + wr * 64 + mi * 16 + (l >> 4) * 4 + r;
        int cg = tN + wc * 64 + ni * 16 + lr;
        float v = acc[mi][ni][r];
        if constexpr (BIAS == 2) v += bias[rg];
        long long off = coff + (long long)rg * ldc + cg;
        if constexpr (OUTM == 0) ((float*)C0)[off] = v;
        else ((unsigned short*)C0)[off] = f2bf(v);
      }
}

// In-place row softmax: fp32 row [Sn] -> normalized bf16 attn in first Sn shorts.
__global__ __launch_bounds__(256) void k_softmax(float* __restrict__ S) {
  const long long row = blockIdx.x;
  float* src = S + row * Sn;
  const int t = threadIdx.x;
  float4 v0 = *(const float4*)(src + t * 8);
  float4 v1 = *(const float4*)(src + t * 8 + 4);
  float m = fmaxf(fmaxf(fmaxf(v0.x, v0.y), fmaxf(v0.z, v0.w)),
                  fmaxf(fmaxf(v1.x, v1.y), fmaxf(v1.z, v1.w)));
#pragma unroll
  for (int off = 32; off > 0; off >>= 1) m = fmaxf(m, __shfl_xor(m, off));
  __shared__ float red[8];
  if ((t & 63) == 0) red[t >> 6] = m;
  __syncthreads();
  m = fmaxf(fmaxf(red[0], red[1]), fmaxf(red[2], red[3]));
  float e[8];
  e[0] = __expf(v0.x - m); e[1] = __expf(v0.y - m);
  e[2] = __expf(v0.z - m); e[3] = __expf(v0.w - m);
  e[4] = __expf(v1.x - m); e[5] = __expf(v1.y - m);
  e[6] = __expf(v1.z - m); e[7] = __expf(v1.w - m);
  float s = ((e[0] + e[1]) + (e[2] + e[3])) + ((e[4] + e[5]) + (e[6] + e[7]));
#pragma unroll
  for (int off = 32; off > 0; off >>= 1) s += __shfl_xor(s, off);
  if ((t & 63) == 0) red[4 + (t >> 6)] = s;
  __syncthreads();
  s = (red[4] + red[5]) + (red[6] + red[7]);
  float inv = 1.0f / s;
  us8 o;
#pragma unroll
  for (int j = 0; j < 8; ++j) o[j] = f2bf(e[j] * inv);
  *(us8*)((unsigned short*)src + t * 8) = o;
}

}  // namespace

extern "C" void kernel_launch(void* const* d_in, const int* in_sizes, int n_in,
                              void* d_out, int out_size, void* d_ws, size_t ws_size,
                              hipStream_t stream) {
  (void)in_sizes; (void)n_in; (void)out_size;
  const float* x1 = (const float*)d_in[0];
  const float* x2 = (const float*)d_in[1];
  const float* x3 = (const float*)d_in[2];
  const float* Wq = (const float*)d_in[3];
  const float* bq = (const float*)d_in[4];
  const float* Wk = (const float*)d_in[5];
  const float* bk = (const float*)d_in[6];
  const float* Wv = (const float*)d_in[7];
  const float* bv = (const float*)d_in[8];
  float* out = (float*)d_out;
  char* ws = (char*)d_ws;

  const size_t MiB = 1048576ull;
  // ws layout (MiB): [0,4) w-hi (Wq|Wk) [4,8) w-lo [8,~) bias_cat
  // [12,44) x1h [44,76) x2h (contig virt A-hi) [76,108) x1l [108,140) x2l
  // [140,172) kh [172,204) kl [204,236) vT ; S fp32 overlays [12,140)
  unsigned short* wqh = (unsigned short*)(ws);
  unsigned short* wql = (unsigned short*)(ws + 4 * MiB);
  float* bias_cat = (float*)(ws + 8 * MiB);
  unsigned short* x1h = (unsigned short*)(ws + 12 * MiB);
  unsigned short* x2h = (unsigned short*)(ws + 44 * MiB);
  unsigned short* x1l = (unsigned short*)(ws + 76 * MiB);
  unsigned short* x2l = (unsigned short*)(ws + 108 * MiB);
  unsigned short* kh  = (unsigned short*)(ws + 140 * MiB);
  unsigned short* kl  = (unsigned short*)(ws + 172 * MiB);
  unsigned short* vT  = (unsigned short*)(ws + 204 * MiB);
  float* S = (float*)(ws + 12 * MiB);
  if (ws_size < 236 * MiB) return;  // visible failure => ws probe

  unsigned short* qh = (unsigned short*)d_out;  // q hi/lo interleaved per batch

  const int nx = Mn * Cn, nw = Cn * Cn;
  k_split<<<2048, 256, 0, stream>>>(x1, x1h, x1l, nx);
  k_split<<<2048, 256, 0, stream>>>(x2, x2h, x2l, nx);
  k_split<<<256, 256, 0, stream>>>(Wq, wqh, wql, nw);
  k_split<<<256, 256, 0, stream>>>(Wk, wqh + 1048576, wql + 1048576, nw);
  k_bias2<<<4, 256, 0, stream>>>(bq, bk, bias_cat);

  // merged Q+K projection, 8-phase 256^2 (virtual M=32768)
  gemm8<0><<<512, 512, 0, stream>>>(x1h, x1l, wqh, wql, bias_cat,
                                    qh, kh, kl, nullptr);
  // vT[d][s] = (x3 @ Wv^T + bv)^T : A=Wv (fp32 reg-staged), B^T=x3, row bias
  dim3 gv(Mn / 128, Cn / 128, 1);
  gemm<3, 3, 2, 1><<<gv, 256, 0, stream>>>(Wv, x3, bv, vT, Cn, Cn, Cn, Mn, 0, 0, 0);
  // scores[b] = q[b] @ k[b]^T, 8-phase 256^2 per batch (NO 1/sqrt(d))
  gemm8<1><<<512, 512, 0, stream>>>(qh, nullptr, kh, kl, nullptr,
                                    nullptr, nullptr, nullptr, S);
  // in-place softmax -> bf16 attn rows
  k_softmax<<<Mn, 256, 0, stream>>>(S);
  // out[b] = attn[b] @ v[b] : A=attn (bf16, lda 2*Sn), B^T=vT cols b*Sn..
  dim3 gp(Cn / 128, Sn / 128, Bn);
  gemm<0, 0, 0, 0><<<gp, 256, 0, stream>>>(
      (unsigned short*)S, vT, nullptr, out,
      Sn, 2 * Sn, Mn, Cn,
      (long long)Sn * Sn * 2, (long long)Sn, (long long)Sn * Cn);
}

// Round 8
// 725.362 us; speedup vs baseline: 1.0632x; 1.0139x over previous
//
#include <hip/hip_runtime.h>
#include <stdint.h>

namespace {

constexpr int Bn = 8;
constexpr int Sn = 2048;
constexpr int Cn = 1024;
constexpr int Mn = Bn * Sn;  // 16384

typedef float f32x4 __attribute__((ext_vector_type(4)));
typedef __bf16 bf16x8 __attribute__((ext_vector_type(8)));
typedef unsigned short us8 __attribute__((ext_vector_type(8)));

__device__ __forceinline__ unsigned short f2bf(float f) {
  uint32_t x = __float_as_uint(f);
  x += 0x7fffu + ((x >> 16) & 1u);  // round-to-nearest-even
  return (unsigned short)(x >> 16);
}
__device__ __forceinline__ float bf2f(unsigned short u) {
  return __uint_as_float(((uint32_t)u) << 16);
}

__device__ __forceinline__ void stage16(const unsigned short* g, unsigned short* l) {
  __builtin_amdgcn_global_load_lds(
      (const __attribute__((address_space(1))) void*)g,
      (__attribute__((address_space(3))) void*)l, 16, 0, 0);
}

// f32 -> (hi bf16, lo bf16) split, vectorized
__global__ __launch_bounds__(256) void k_split(const float* __restrict__ src,
                                               unsigned short* __restrict__ hi,
                                               unsigned short* __restrict__ lo, int n) {
  int stride = gridDim.x * blockDim.x;
  for (int i = blockIdx.x * blockDim.x + threadIdx.x; i * 4 < n; i += stride) {
    int j = i * 4;
    float4 v = *(const float4*)(src + j);
    ushort4 h, l;
    h.x = f2bf(v.x); l.x = f2bf(v.x - bf2f(h.x));
    h.y = f2bf(v.y); l.y = f2bf(v.y - bf2f(h.y));
    h.z = f2bf(v.z); l.z = f2bf(v.z - bf2f(h.z));
    h.w = f2bf(v.w); l.w = f2bf(v.w - bf2f(h.w));
    *(ushort4*)(hi + j) = h;
    *(ushort4*)(lo + j) = l;
  }
}

__global__ __launch_bounds__(256) void k_cast(const float* __restrict__ src,
                                              unsigned short* __restrict__ dst, int n) {
  int stride = gridDim.x * blockDim.x;
  for (int i = blockIdx.x * blockDim.x + threadIdx.x; i * 4 < n; i += stride) {
    int j = i * 4;
    float4 v = *(const float4*)(src + j);
    ushort4 h;
    h.x = f2bf(v.x); h.y = f2bf(v.y); h.z = f2bf(v.z); h.w = f2bf(v.w);
    *(ushort4*)(dst + j) = h;
  }
}

__global__ __launch_bounds__(256) void k_bias2(const float* __restrict__ a,
                                               const float* __restrict__ b,
                                               float* __restrict__ dst) {
  int t = threadIdx.x + blockIdx.x * 256;
  if (t < Cn) { dst[t] = a[t]; dst[Cn + t] = b[t]; }
}

// ---------------------------------------------------------------------------
// 2-barrier 128x128 SPLIT GEMM (3-term hi/lo MFMA emulation), K=1024, BK=32.
// Proven 954 TF in-problem (round 2). XCD-chunked 1-D decode + T2 involution
// swizzle (source slot pre-swizzled, read slot XORed; LDS dest linear).
// SM 0: merged QK-projection, virtual M=32768 (side=tM>=Mn selects Wk);
//       q rows -> hi/lo interleaved per batch into O0 (d_out), k -> O1/O2.
// SM 1: QK^T per batch (batch = XCD chunk), fp32 scores out (NO 1/sqrt(d)).
// ---------------------------------------------------------------------------
template <int SM>
__global__ __launch_bounds__(256) void gemm2s(
    const unsigned short* __restrict__ Ah, const unsigned short* __restrict__ Al,
    const unsigned short* __restrict__ Bh, const unsigned short* __restrict__ Bl,
    const float* __restrict__ bias,
    unsigned short* __restrict__ O0, unsigned short* __restrict__ O1,
    unsigned short* __restrict__ O2, float* __restrict__ Sout) {
  __shared__ unsigned short smem[16384];  // Ah,Al,Bh,Bl tiles 128x32 (8 KB each)
  unsigned short* As  = smem;
  unsigned short* As2 = smem + 4096;
  unsigned short* Bs  = smem + 8192;
  unsigned short* Bs2 = smem + 12288;

  const int bid = blockIdx.x;
  const int chunk = bid & 7;   // XCD id (round-robin dispatch)
  const int r = bid >> 3;      // 0..255 within this XCD's contiguous span

  int tM, tN, side = 0, z = 0;
  const unsigned short *a0, *a1, *b0, *b1;
  if constexpr (SM == 0) {
    int y = chunk * 32 + (r >> 3);   // XCD-contiguous A rows (~1x A fetch)
    int x = r & 7;
    tM = y * 128; tN = x * 128;
    side = (y >= 128);
    a0 = Ah; a1 = Al;
    b0 = Bh + side * 1048576; b1 = Bl + side * 1048576;
  } else {
    z = chunk;                        // batch per XCD
    int ys = r >> 6, x = (r >> 2) & 15, y4 = r & 3;  // 4-row supertiles
    tM = (ys * 4 + y4) * 128; tN = x * 128;
    a0 = Ah + (long long)z * 4194304; a1 = a0 + 2097152;
    b0 = Bh + (long long)z * 2097152; b1 = Bl + (long long)z * 2097152;
  }

  const int t = threadIdx.x;
  const int l = t & 63;
  const int w = t >> 6;
  const int wr = w >> 1, wc = w & 1;
  const int lr = l & 15;
  const int lkq = l >> 4;
  // T2 involution: source slot pre-swizzle (stage) + read slot XOR (same map)
  const int ssw = ((t & 3) ^ ((t >> 3) & 3)) * 8;
  const int rsw = (lkq ^ ((lr >> 1) & 3)) * 8;

  f32x4 acc[4][4] = {};

  for (int k0 = 0; k0 < 1024; k0 += 32) {
#pragma unroll
    for (int c = 0; c < 2; ++c) {
      int idx = c * 256 + t;
      int row = idx >> 2;
      long long ao = (long long)(tM + row) * 1024 + k0 + ssw;
      long long bo = (long long)(tN + row) * 1024 + k0 + ssw;
      stage16(a0 + ao, As  + idx * 8);
      stage16(a1 + ao, As2 + idx * 8);
      stage16(b0 + bo, Bs  + idx * 8);
      stage16(b1 + bo, Bs2 + idx * 8);
    }
    __syncthreads();
    bf16x8 ah[4], al[4], bh[4], bl[4];
#pragma unroll
    for (int i = 0; i < 4; ++i) {
      int rowb = (wr * 64 + i * 16 + lr) * 32;
      int rowc = (wc * 64 + i * 16 + lr) * 32;
      ah[i] = *(const bf16x8*)&As[rowb + rsw];
      al[i] = *(const bf16x8*)&As2[rowb + rsw];
      bh[i] = *(const bf16x8*)&Bs[rowc + rsw];
      bl[i] = *(const bf16x8*)&Bs2[rowc + rsw];
    }
#pragma unroll
    for (int mi = 0; mi < 4; ++mi)
#pragma unroll
      for (int ni = 0; ni < 4; ++ni) {
        acc[mi][ni] = __builtin_amdgcn_mfma_f32_16x16x32_bf16(ah[mi], bh[ni], acc[mi][ni], 0, 0, 0);
        acc[mi][ni] = __builtin_amdgcn_mfma_f32_16x16x32_bf16(ah[mi], bl[ni], acc[mi][ni], 0, 0, 0);
        acc[mi][ni] = __builtin_amdgcn_mfma_f32_16x16x32_bf16(al[mi], bh[ni], acc[mi][ni], 0, 0, 0);
      }
    __syncthreads();
  }

#pragma unroll
  for (int mi = 0; mi < 4; ++mi)
#pragma unroll
    for (int ni = 0; ni < 4; ++ni)
#pragma unroll
      for (int r2 = 0; r2 < 4; ++r2) {
        int rg = tM + wr * 64 + mi * 16 + (l >> 4) * 4 + r2;
        int cg = tN + wc * 64 + ni * 16 + lr;
        float v = acc[mi][ni][r2];
        if constexpr (SM == 0) {
          v += bias[side * 1024 + cg];
          unsigned short h = f2bf(v);
          unsigned short lo = f2bf(v - bf2f(h));
          if (!side) {
            long long off = (long long)(rg >> 11) * 4194304ll +
                            (long long)(rg & 2047) * 1024 + cg;
            O0[off] = h;
            O0[off + 2097152ll] = lo;
          } else {
            long long off = (long long)(rg - Mn) * 1024 + cg;
            O1[off] = h;
            O2[off] = lo;
          }
        } else {
          Sout[(long long)z * 4194304ll + (long long)rg * 2048 + cg] = v;
        }
      }
}

// ---------------------------------------------------------------------------
// 2-barrier 128x128 PLAIN bf16 GEMM, gload_lds staging + same swizzle.
// PM 0: Vproj  vT[d][s] = (x3 @ Wv^T + bv)^T : A=Wv(bf16), B=x3(bf16),
//       per-row bias, bf16 out ldc=Mn. K=1024.
// PM 1: PV     out[b] = attn[b] @ v[b] : A=attn (bf16 rows, lda 2*Sn),
//       B=vT (+z*Sn, ldb Mn), fp32 out. K=2048. batch = XCD chunk.
// ---------------------------------------------------------------------------
template <int PM>
__global__ __launch_bounds__(256) void gemm2p(
    const unsigned short* __restrict__ A, const unsigned short* __restrict__ B,
    const float* __restrict__ bias, unsigned short* __restrict__ Obf,
    float* __restrict__ Of) {
  __shared__ unsigned short smem[8192];
  unsigned short* As = smem;
  unsigned short* Bs = smem + 4096;

  const int bid = blockIdx.x;
  const int chunk = bid & 7;
  const int r = bid >> 3;  // 0..127

  int tM, tN, z = 0;
  const unsigned short *ap, *bp;
  int lda, ldb;
  if constexpr (PM == 0) {
    int xg = chunk * 16 + (r >> 3);  // XCD-contiguous B cols
    int y = r & 7;
    tN = xg * 128; tM = y * 128;
    ap = A; bp = B; lda = 1024; ldb = 1024;
  } else {
    z = chunk;
    int x = r >> 4, y = r & 15;
    tN = x * 128; tM = y * 128;
    ap = A + (long long)z * 8388608;  // attn batch (fp32-row region, shorts)
    bp = B + (long long)z * 2048;     // vT column slice
    lda = 4096; ldb = 16384;
  }
  constexpr int K = (PM == 0) ? 1024 : 2048;

  const int t = threadIdx.x;
  const int l = t & 63;
  const int w = t >> 6;
  const int wr = w >> 1, wc = w & 1;
  const int lr = l & 15;
  const int lkq = l >> 4;
  const int ssw = ((t & 3) ^ ((t >> 3) & 3)) * 8;
  const int rsw = (lkq ^ ((lr >> 1) & 3)) * 8;

  f32x4 acc[4][4] = {};

  for (int k0 = 0; k0 < K; k0 += 32) {
#pragma unroll
    for (int c = 0; c < 2; ++c) {
      int idx = c * 256 + t;
      int row = idx >> 2;
      stage16(ap + (long long)(tM + row) * lda + k0 + ssw, As + idx * 8);
      stage16(bp + (long long)(tN + row) * ldb + k0 + ssw, Bs + idx * 8);
    }
    __syncthreads();
    bf16x8 av[4], bv[4];
#pragma unroll
    for (int i = 0; i < 4; ++i) {
      av[i] = *(const bf16x8*)&As[(wr * 64 + i * 16 + lr) * 32 + rsw];
      bv[i] = *(const bf16x8*)&Bs[(wc * 64 + i * 16 + lr) * 32 + rsw];
    }
#pragma unroll
    for (int mi = 0; mi < 4; ++mi)
#pragma unroll
      for (int ni = 0; ni < 4; ++ni)
        acc[mi][ni] = __builtin_amdgcn_mfma_f32_16x16x32_bf16(av[mi], bv[ni], acc[mi][ni], 0, 0, 0);
    __syncthreads();
  }

#pragma unroll
  for (int mi = 0; mi < 4; ++mi)
#pragma unroll
    for (int ni = 0; ni < 4; ++ni)
#pragma unroll
      for (int r2 = 0; r2 < 4; ++r2) {
        int rg = tM + wr * 64 + mi * 16 + (l >> 4) * 4 + r2;
        int cg = tN + wc * 64 + ni * 16 + lr;
        float v = acc[mi][ni][r2];
        if constexpr (PM == 0) {
          v += bias[rg];
          Obf[(long long)rg * 16384 + cg] = f2bf(v);
        } else {
          Of[(long long)z * 2097152ll + (long long)rg * 1024 + cg] = v;
        }
      }
}

// In-place row softmax: fp32 row [Sn] -> normalized bf16 attn in first Sn shorts.
// Reads complete before first barrier, writes after the second -> race-free.
__global__ __launch_bounds__(256) void k_softmax(float* __restrict__ S) {
  const long long row = blockIdx.x;
  float* src = S + row * Sn;
  const int t = threadIdx.x;
  float4 v0 = *(const float4*)(src + t * 8);
  float4 v1 = *(const float4*)(src + t * 8 + 4);
  float m = fmaxf(fmaxf(fmaxf(v0.x, v0.y), fmaxf(v0.z, v0.w)),
                  fmaxf(fmaxf(v1.x, v1.y), fmaxf(v1.z, v1.w)));
#pragma unroll
  for (int off = 32; off > 0; off >>= 1) m = fmaxf(m, __shfl_xor(m, off));
  __shared__ float red[8];
  if ((t & 63) == 0) red[t >> 6] = m;
  __syncthreads();
  m = fmaxf(fmaxf(red[0], red[1]), fmaxf(red[2], red[3]));
  float e[8];
  e[0] = __expf(v0.x - m); e[1] = __expf(v0.y - m);
  e[2] = __expf(v0.z - m); e[3] = __expf(v0.w - m);
  e[4] = __expf(v1.x - m); e[5] = __expf(v1.y - m);
  e[6] = __expf(v1.z - m); e[7] = __expf(v1.w - m);
  float s = ((e[0] + e[1]) + (e[2] + e[3])) + ((e[4] + e[5]) + (e[6] + e[7]));
#pragma unroll
  for (int off = 32; off > 0; off >>= 1) s += __shfl_xor(s, off);
  if ((t & 63) == 0) red[4 + (t >> 6)] = s;
  __syncthreads();
  s = (red[4] + red[5]) + (red[6] + red[7]);
  float inv = 1.0f / s;
  us8 o;
#pragma unroll
  for (int j = 0; j < 8; ++j) o[j] = f2bf(e[j] * inv);
  *(us8*)((unsigned short*)src + t * 8) = o;
}

}  // namespace

extern "C" void kernel_launch(void* const* d_in, const int* in_sizes, int n_in,
                              void* d_out, int out_size, void* d_ws, size_t ws_size,
                              hipStream_t stream) {
  (void)in_sizes; (void)n_in; (void)out_size;
  const float* x1 = (const float*)d_in[0];
  const float* x2 = (const float*)d_in[1];
  const float* x3 = (const float*)d_in[2];
  const float* Wq = (const float*)d_in[3];
  const float* bq = (const float*)d_in[4];
  const float* Wk = (const float*)d_in[5];
  const float* bk = (const float*)d_in[6];
  const float* Wv = (const float*)d_in[7];
  const float* bv = (const float*)d_in[8];
  float* out = (float*)d_out;
  char* ws = (char*)d_ws;

  const size_t MiB = 1048576ull;
  // ws layout (MiB): [0,4) w-hi (Wq|Wk) [4,8) w-lo [8,9) bias_cat [9,11) wvb
  // [12,44) x3b -> then x1h (x3b dead after Vproj, which runs FIRST)
  // [44,76) x2h [76,108) x1l [108,140) x2l ; S fp32 overlays [12,140)
  // [140,172) kh [172,204) kl [204,236) vT.  NEED 236 <= proven ws (>=266).
  unsigned short* wqh = (unsigned short*)(ws);
  unsigned short* wql = (unsigned short*)(ws + 4 * MiB);
  float* bias_cat = (float*)(ws + 8 * MiB);
  unsigned short* wvb = (unsigned short*)(ws + 9 * MiB);
  unsigned short* x3b = (unsigned short*)(ws + 12 * MiB);
  unsigned short* x1h = (unsigned short*)(ws + 12 * MiB);
  unsigned short* x2h = (unsigned short*)(ws + 44 * MiB);
  unsigned short* x1l = (unsigned short*)(ws + 76 * MiB);
  unsigned short* x2l = (unsigned short*)(ws + 108 * MiB);
  unsigned short* kh  = (unsigned short*)(ws + 140 * MiB);
  unsigned short* kl  = (unsigned short*)(ws + 172 * MiB);
  unsigned short* vT  = (unsigned short*)(ws + 204 * MiB);
  float* S = (float*)(ws + 12 * MiB);
  if (ws_size < 236 * MiB) return;  // visible failure => ws probe

  unsigned short* qh = (unsigned short*)d_out;  // q hi/lo interleaved per batch

  const int nx = Mn * Cn, nw = Cn * Cn;
  // 1) V path first: x3b overlays the future x1h region.
  k_cast<<<2048, 256, 0, stream>>>(x3, x3b, nx);
  k_cast<<<256, 256, 0, stream>>>(Wv, wvb, nw);
  gemm2p<0><<<1024, 256, 0, stream>>>(wvb, x3b, bv, vT, nullptr);
  // 2) splits (x1h overwrites dead x3b).
  k_split<<<2048, 256, 0, stream>>>(x1, x1h, x1l, nx);
  k_split<<<2048, 256, 0, stream>>>(x2, x2h, x2l, nx);
  k_split<<<256, 256, 0, stream>>>(Wq, wqh, wql, nw);
  k_split<<<256, 256, 0, stream>>>(Wk, wqh + 1048576, wql + 1048576, nw);
  k_bias2<<<4, 256, 0, stream>>>(bq, bk, bias_cat);
  // 3) merged Q+K projection (virtual M=32768), split 3-term, 954-TF structure.
  gemm2s<0><<<2048, 256, 0, stream>>>(x1h, x1l, wqh, wql, bias_cat,
                                      qh, kh, kl, nullptr);
  // 4) scores = q @ k^T per batch (split precision, fp32, NO 1/sqrt(d)).
  gemm2s<1><<<2048, 256, 0, stream>>>(qh, nullptr, kh, kl, nullptr,
                                      nullptr, nullptr, nullptr, S);
  // 5) in-place softmax -> bf16 attn rows.
  k_softmax<<<Mn, 256, 0, stream>>>(S);
  // 6) out[b] = attn[b] @ v[b].
  gemm2p<1><<<1024, 256, 0, stream>>>((unsigned short*)S, vT, nullptr, nullptr, out);
}

// Round 9
// 722.133 us; speedup vs baseline: 1.0679x; 1.0045x over previous
//
#include <hip/hip_runtime.h>
#include <stdint.h>

namespace {

constexpr int Bn = 8;
constexpr int Sn = 2048;
constexpr int Cn = 1024;
constexpr int Mn = Bn * Sn;  // 16384

typedef float f32x4 __attribute__((ext_vector_type(4)));
typedef __bf16 bf16x8 __attribute__((ext_vector_type(8)));
typedef unsigned short us8 __attribute__((ext_vector_type(8)));

__device__ __forceinline__ unsigned short f2bf(float f) {
  uint32_t x = __float_as_uint(f);
  x += 0x7fffu + ((x >> 16) & 1u);  // round-to-nearest-even
  return (unsigned short)(x >> 16);
}
__device__ __forceinline__ float bf2f(unsigned short u) {
  return __uint_as_float(((uint32_t)u) << 16);
}

__device__ __forceinline__ void stage16(const unsigned short* g, unsigned short* l) {
  __builtin_amdgcn_global_load_lds(
      (const __attribute__((address_space(1))) void*)g,
      (__attribute__((address_space(3))) void*)l, 16, 0, 0);
}

// f32 -> (hi bf16, lo bf16) split, vectorized
__global__ __launch_bounds__(256) void k_split(const float* __restrict__ src,
                                               unsigned short* __restrict__ hi,
                                               unsigned short* __restrict__ lo, int n) {
  int stride = gridDim.x * blockDim.x;
  for (int i = blockIdx.x * blockDim.x + threadIdx.x; i * 4 < n; i += stride) {
    int j = i * 4;
    float4 v = *(const float4*)(src + j);
    ushort4 h, l;
    h.x = f2bf(v.x); l.x = f2bf(v.x - bf2f(h.x));
    h.y = f2bf(v.y); l.y = f2bf(v.y - bf2f(h.y));
    h.z = f2bf(v.z); l.z = f2bf(v.z - bf2f(h.z));
    h.w = f2bf(v.w); l.w = f2bf(v.w - bf2f(h.w));
    *(ushort4*)(hi + j) = h;
    *(ushort4*)(lo + j) = l;
  }
}

__global__ __launch_bounds__(256) void k_cast(const float* __restrict__ src,
                                              unsigned short* __restrict__ dst, int n) {
  int stride = gridDim.x * blockDim.x;
  for (int i = blockIdx.x * blockDim.x + threadIdx.x; i * 4 < n; i += stride) {
    int j = i * 4;
    float4 v = *(const float4*)(src + j);
    ushort4 h;
    h.x = f2bf(v.x); h.y = f2bf(v.y); h.z = f2bf(v.z); h.w = f2bf(v.w);
    *(ushort4*)(dst + j) = h;
  }
}

__global__ __launch_bounds__(256) void k_bias2(const float* __restrict__ a,
                                               const float* __restrict__ b,
                                               float* __restrict__ dst) {
  int t = threadIdx.x + blockIdx.x * 256;
  if (t < Cn) { dst[t] = a[t]; dst[Cn + t] = b[t]; }
}

// ---------------------------------------------------------------------------
// 2-barrier 128x128 SPLIT GEMM (3-term hi/lo MFMA), K=1024, BK=32 — the exact
// round-2 954 TF structure: linear staging + linear reads, natural grids.
// SM 0: merged QK-projection, grid (8, 256) col-fastest; side = tM>=Mn.
//       q rows -> hi/lo interleaved per batch into O0 (d_out), k -> O1/O2.
// SM 1: QK^T, grid (16,16,8) z=batch; fp32 scores out (NO 1/sqrt(d)).
// ---------------------------------------------------------------------------
template <int SM>
__global__ __launch_bounds__(256) void gemm2s(
    const unsigned short* __restrict__ Ah, const unsigned short* __restrict__ Al,
    const unsigned short* __restrict__ Bh, const unsigned short* __restrict__ Bl,
    const float* __restrict__ bias,
    unsigned short* __restrict__ O0, unsigned short* __restrict__ O1,
    unsigned short* __restrict__ O2, float* __restrict__ Sout) {
  __shared__ unsigned short smem[16384];  // Ah,Al,Bh,Bl tiles 128x32 (8 KB each)
  unsigned short* As  = smem;
  unsigned short* As2 = smem + 4096;
  unsigned short* Bs  = smem + 8192;
  unsigned short* Bs2 = smem + 12288;

  int tM, tN, side = 0, z = 0;
  const unsigned short *a0, *a1, *b0, *b1;
  if constexpr (SM == 0) {
    tN = blockIdx.x * 128;          // col-fastest (round-4 measured 250 us)
    tM = blockIdx.y * 128;
    side = (tM >= Mn);
    a0 = Ah; a1 = Al;
    b0 = Bh + side * 1048576; b1 = Bl + side * 1048576;
  } else {
    tN = blockIdx.x * 128;          // round-2 measured 216 us
    tM = blockIdx.y * 128;
    z = blockIdx.z;
    a0 = Ah + (long long)z * 4194304; a1 = a0 + 2097152;
    b0 = Bh + (long long)z * 2097152; b1 = Bl + (long long)z * 2097152;
  }

  const int t = threadIdx.x;
  const int l = t & 63;
  const int w = t >> 6;
  const int wr = w >> 1, wc = w & 1;
  const int lr = l & 15;
  const int lk = (l >> 4) * 8;

  f32x4 acc[4][4] = {};

  for (int k0 = 0; k0 < 1024; k0 += 32) {
#pragma unroll
    for (int c = 0; c < 2; ++c) {
      int idx = c * 256 + t;
      int row = idx >> 2;
      int co = (idx & 3) * 8;
      long long ao = (long long)(tM + row) * 1024 + k0 + co;
      stage16(a0 + ao, As  + idx * 8);
      stage16(a1 + ao, As2 + idx * 8);
    }
#pragma unroll
    for (int c = 0; c < 2; ++c) {
      int idx = c * 256 + t;
      int row = idx >> 2;
      int co = (idx & 3) * 8;
      long long bo = (long long)(tN + row) * 1024 + k0 + co;
      stage16(b0 + bo, Bs  + idx * 8);
      stage16(b1 + bo, Bs2 + idx * 8);
    }
    __syncthreads();
    bf16x8 ah[4], al[4], bh[4], bl[4];
#pragma unroll
    for (int i = 0; i < 4; ++i) {
      int rowb = (wr * 64 + i * 16 + lr) * 32;
      int rowc = (wc * 64 + i * 16 + lr) * 32;
      ah[i] = *(const bf16x8*)&As[rowb + lk];
      al[i] = *(const bf16x8*)&As2[rowb + lk];
      bh[i] = *(const bf16x8*)&Bs[rowc + lk];
      bl[i] = *(const bf16x8*)&Bs2[rowc + lk];
    }
#pragma unroll
    for (int mi = 0; mi < 4; ++mi)
#pragma unroll
      for (int ni = 0; ni < 4; ++ni) {
        acc[mi][ni] = __builtin_amdgcn_mfma_f32_16x16x32_bf16(ah[mi], bh[ni], acc[mi][ni], 0, 0, 0);
        acc[mi][ni] = __builtin_amdgcn_mfma_f32_16x16x32_bf16(ah[mi], bl[ni], acc[mi][ni], 0, 0, 0);
        acc[mi][ni] = __builtin_amdgcn_mfma_f32_16x16x32_bf16(al[mi], bh[ni], acc[mi][ni], 0, 0, 0);
      }
    __syncthreads();
  }

#pragma unroll
  for (int mi = 0; mi < 4; ++mi)
#pragma unroll
    for (int ni = 0; ni < 4; ++ni)
#pragma unroll
      for (int r2 = 0; r2 < 4; ++r2) {
        int rg = tM + wr * 64 + mi * 16 + (l >> 4) * 4 + r2;
        int cg = tN + wc * 64 + ni * 16 + lr;
        float v = acc[mi][ni][r2];
        if constexpr (SM == 0) {
          v += bias[side * 1024 + cg];
          unsigned short h = f2bf(v);
          unsigned short lo = f2bf(v - bf2f(h));
          if (!side) {
            long long off = (long long)(rg >> 11) * 4194304ll +
                            (long long)(rg & 2047) * 1024 + cg;
            O0[off] = h;
            O0[off + 2097152ll] = lo;
          } else {
            long long off = (long long)(rg - Mn) * 1024 + cg;
            O1[off] = h;
            O2[off] = lo;
          }
        } else {
          Sout[(long long)z * 4194304ll + (long long)rg * 2048 + cg] = v;
        }
      }
}

// ---------------------------------------------------------------------------
// 2-barrier 128x128 PLAIN bf16 GEMM, linear staging/reads, natural grids.
// PM 0: Vproj  vT[d][s] = (x3 @ Wv^T + bv)^T : A=Wv, B=x3, per-row bias,
//       bf16 out ldc=Mn, K=1024, grid (128, 8) col-fastest.
// PM 1: PV     out[b] = attn[b] @ v[b] : A=attn (bf16 rows, lda 2*Sn),
//       B=vT (+z*Sn), fp32 out, K=2048, grid (8,16,8) z=batch.
// ---------------------------------------------------------------------------
template <int PM>
__global__ __launch_bounds__(256) void gemm2p(
    const unsigned short* __restrict__ A, const unsigned short* __restrict__ B,
    const float* __restrict__ bias, unsigned short* __restrict__ Obf,
    float* __restrict__ Of) {
  __shared__ unsigned short smem[8192];
  unsigned short* As = smem;
  unsigned short* Bs = smem + 4096;

  int tM, tN, z = 0;
  const unsigned short *ap, *bp;
  int lda, ldb;
  tN = blockIdx.x * 128;
  tM = blockIdx.y * 128;
  if constexpr (PM == 0) {
    ap = A; bp = B; lda = 1024; ldb = 1024;
  } else {
    z = blockIdx.z;
    ap = A + (long long)z * 8388608;  // attn batch (fp32-row region, shorts)
    bp = B + (long long)z * 2048;     // vT column slice
    lda = 4096; ldb = 16384;
  }
  constexpr int K = (PM == 0) ? 1024 : 2048;

  const int t = threadIdx.x;
  const int l = t & 63;
  const int w = t >> 6;
  const int wr = w >> 1, wc = w & 1;
  const int lr = l & 15;
  const int lk = (l >> 4) * 8;

  f32x4 acc[4][4] = {};

  for (int k0 = 0; k0 < K; k0 += 32) {
#pragma unroll
    for (int c = 0; c < 2; ++c) {
      int idx = c * 256 + t;
      int row = idx >> 2;
      int co = (idx & 3) * 8;
      stage16(ap + (long long)(tM + row) * lda + k0 + co, As + idx * 8);
      stage16(bp + (long long)(tN + row) * ldb + k0 + co, Bs + idx * 8);
    }
    __syncthreads();
    bf16x8 av[4], bv[4];
#pragma unroll
    for (int i = 0; i < 4; ++i) {
      av[i] = *(const bf16x8*)&As[(wr * 64 + i * 16 + lr) * 32 + lk];
      bv[i] = *(const bf16x8*)&Bs[(wc * 64 + i * 16 + lr) * 32 + lk];
    }
#pragma unroll
    for (int mi = 0; mi < 4; ++mi)
#pragma unroll
      for (int ni = 0; ni < 4; ++ni)
        acc[mi][ni] = __builtin_amdgcn_mfma_f32_16x16x32_bf16(av[mi], bv[ni], acc[mi][ni], 0, 0, 0);
    __syncthreads();
  }

#pragma unroll
  for (int mi = 0; mi < 4; ++mi)
#pragma unroll
    for (int ni = 0; ni < 4; ++ni)
#pragma unroll
      for (int r2 = 0; r2 < 4; ++r2) {
        int rg = tM + wr * 64 + mi * 16 + (l >> 4) * 4 + r2;
        int cg = tN + wc * 64 + ni * 16 + lr;
        float v = acc[mi][ni][r2];
        if constexpr (PM == 0) {
          v += bias[rg];
          Obf[(long long)rg * 16384 + cg] = f2bf(v);
        } else {
          Of[(long long)z * 2097152ll + (long long)rg * 1024 + cg] = v;
        }
      }
}

// In-place row softmax: fp32 row [Sn] -> normalized bf16 attn in first Sn shorts.
// Reads complete before first barrier, writes after the second -> race-free.
__global__ __launch_bounds__(256) void k_softmax(float* __restrict__ S) {
  const long long row = blockIdx.x;
  float* src = S + row * Sn;
  const int t = threadIdx.x;
  float4 v0 = *(const float4*)(src + t * 8);
  float4 v1 = *(const float4*)(src + t * 8 + 4);
  float m = fmaxf(fmaxf(fmaxf(v0.x, v0.y), fmaxf(v0.z, v0.w)),
                  fmaxf(fmaxf(v1.x, v1.y), fmaxf(v1.z, v1.w)));
#pragma unroll
  for (int off = 32; off > 0; off >>= 1) m = fmaxf(m, __shfl_xor(m, off));
  __shared__ float red[8];
  if ((t & 63) == 0) red[t >> 6] = m;
  __syncthreads();
  m = fmaxf(fmaxf(red[0], red[1]), fmaxf(red[2], red[3]));
  float e[8];
  e[0] = __expf(v0.x - m); e[1] = __expf(v0.y - m);
  e[2] = __expf(v0.z - m); e[3] = __expf(v0.w - m);
  e[4] = __expf(v1.x - m); e[5] = __expf(v1.y - m);
  e[6] = __expf(v1.z - m); e[7] = __expf(v1.w - m);
  float s = ((e[0] + e[1]) + (e[2] + e[3])) + ((e[4] + e[5]) + (e[6] + e[7]));
#pragma unroll
  for (int off = 32; off > 0; off >>= 1) s += __shfl_xor(s, off);
  if ((t & 63) == 0) red[4 + (t >> 6)] = s;
  __syncthreads();
  s = (red[4] + red[5]) + (red[6] + red[7]);
  float inv = 1.0f / s;
  us8 o;
#pragma unroll
  for (int j = 0; j < 8; ++j) o[j] = f2bf(e[j] * inv);
  *(us8*)((unsigned short*)src + t * 8) = o;
}

}  // namespace

extern "C" void kernel_launch(void* const* d_in, const int* in_sizes, int n_in,
                              void* d_out, int out_size, void* d_ws, size_t ws_size,
                              hipStream_t stream) {
  (void)in_sizes; (void)n_in; (void)out_size;
  const float* x1 = (const float*)d_in[0];
  const float* x2 = (const float*)d_in[1];
  const float* x3 = (const float*)d_in[2];
  const float* Wq = (const float*)d_in[3];
  const float* bq = (const float*)d_in[4];
  const float* Wk = (const float*)d_in[5];
  const float* bk = (const float*)d_in[6];
  const float* Wv = (const float*)d_in[7];
  const float* bv = (const float*)d_in[8];
  float* out = (float*)d_out;
  char* ws = (char*)d_ws;

  const size_t MiB = 1048576ull;
  // ws layout (MiB): [0,4) w-hi (Wq|Wk) [4,8) w-lo [8,9) bias_cat [9,11) wvb
  // [12,44) x3b -> then x1h (x3b dead after Vproj, which runs FIRST)
  // [44,76) x2h [76,108) x1l [108,140) x2l ; S fp32 overlays [12,140)
  // [140,172) kh [172,204) kl [204,236) vT.  NEED 236 <= proven ws (>=266).
  unsigned short* wqh = (unsigned short*)(ws);
  unsigned short* wql = (unsigned short*)(ws + 4 * MiB);
  float* bias_cat = (float*)(ws + 8 * MiB);
  unsigned short* wvb = (unsigned short*)(ws + 9 * MiB);
  unsigned short* x3b = (unsigned short*)(ws + 12 * MiB);
  unsigned short* x1h = (unsigned short*)(ws + 12 * MiB);
  unsigned short* x2h = (unsigned short*)(ws + 44 * MiB);
  unsigned short* x1l = (unsigned short*)(ws + 76 * MiB);
  unsigned short* x2l = (unsigned short*)(ws + 108 * MiB);
  unsigned short* kh  = (unsigned short*)(ws + 140 * MiB);
  unsigned short* kl  = (unsigned short*)(ws + 172 * MiB);
  unsigned short* vT  = (unsigned short*)(ws + 204 * MiB);
  float* S = (float*)(ws + 12 * MiB);
  if (ws_size < 236 * MiB) return;  // visible failure => ws probe

  unsigned short* qh = (unsigned short*)d_out;  // q hi/lo interleaved per batch

  const int nx = Mn * Cn, nw = Cn * Cn;
  // 1) V path first: x3b overlays the future x1h region.
  k_cast<<<2048, 256, 0, stream>>>(x3, x3b, nx);
  k_cast<<<256, 256, 0, stream>>>(Wv, wvb, nw);
  {
    dim3 gv(128, 8, 1);
    gemm2p<0><<<gv, 256, 0, stream>>>(wvb, x3b, bv, vT, nullptr);
  }
  // 2) splits (x1h overwrites dead x3b).
  k_split<<<2048, 256, 0, stream>>>(x1, x1h, x1l, nx);
  k_split<<<2048, 256, 0, stream>>>(x2, x2h, x2l, nx);
  k_split<<<256, 256, 0, stream>>>(Wq, wqh, wql, nw);
  k_split<<<256, 256, 0, stream>>>(Wk, wqh + 1048576, wql + 1048576, nw);
  k_bias2<<<4, 256, 0, stream>>>(bq, bk, bias_cat);
  // 3) merged Q+K projection (virtual M=32768), col-fastest grid (round-4 cfg).
  {
    dim3 g(8, 256, 1);
    gemm2s<0><<<g, 256, 0, stream>>>(x1h, x1l, wqh, wql, bias_cat,
                                     qh, kh, kl, nullptr);
  }
  // 4) scores = q @ k^T per batch (round-2 cfg: grid (16,16,8)).
  {
    dim3 g(16, 16, 8);
    gemm2s<1><<<g, 256, 0, stream>>>(qh, nullptr, kh, kl, nullptr,
                                     nullptr, nullptr, nullptr, S);
  }
  // 5) in-place softmax -> bf16 attn rows.
  k_softmax<<<Mn, 256, 0, stream>>>(S);
  // 6) out[b] = attn[b] @ v[b] (round-2 cfg: grid (8,16,8)).
  {
    dim3 g(8, 16, 8);
    gemm2p<1><<<g, 256, 0, stream>>>((unsigned short*)S, vT, nullptr, nullptr, out);
  }
}

// Round 10
// 563.256 us; speedup vs baseline: 1.3692x; 1.2821x over previous
//
#include <hip/hip_runtime.h>
#include <stdint.h>

namespace {

constexpr int Bn = 8;
constexpr int Sn = 2048;
constexpr int Cn = 1024;
constexpr int Mn = Bn * Sn;  // 16384
constexpr int NT = 32;       // virtual K-tiles: 2 segs (B-hi, B-lo) x 16, BK=64
constexpr int NI = NT / 2;

typedef float f32x4 __attribute__((ext_vector_type(4)));
typedef _Float16 f16x8 __attribute__((ext_vector_type(8)));
typedef unsigned short us8 __attribute__((ext_vector_type(8)));

__device__ __forceinline__ unsigned short f2bf(float f) {
  uint32_t x = __float_as_uint(f);
  x += 0x7fffu + ((x >> 16) & 1u);  // RNE
  return (unsigned short)(x >> 16);
}
__device__ __forceinline__ unsigned short f2h(float f) {
  _Float16 h = (_Float16)f;
  unsigned short u;
  __builtin_memcpy(&u, &h, 2);
  return u;
}
__device__ __forceinline__ float h2f(unsigned short u) {
  _Float16 h;
  __builtin_memcpy(&h, &u, 2);
  return (float)h;
}

__device__ __forceinline__ void stage16(const unsigned short* g, unsigned short* l) {
  __builtin_amdgcn_global_load_lds(
      (const __attribute__((address_space(1))) void*)g,
      (__attribute__((address_space(3))) void*)l, 16, 0, 0);
}

// f32 -> fp16 cast, vectorized
__global__ __launch_bounds__(256) void k_cast16(const float* __restrict__ src,
                                                unsigned short* __restrict__ dst, int n) {
  int stride = gridDim.x * blockDim.x;
  for (int i = blockIdx.x * blockDim.x + threadIdx.x; i * 4 < n; i += stride) {
    int j = i * 4;
    float4 v = *(const float4*)(src + j);
    ushort4 h;
    h.x = f2h(v.x); h.y = f2h(v.y); h.z = f2h(v.z); h.w = f2h(v.w);
    *(ushort4*)(dst + j) = h;
  }
}

// f32 -> (hi fp16, lo fp16) split
__global__ __launch_bounds__(256) void k_split16(const float* __restrict__ src,
                                                 unsigned short* __restrict__ hi,
                                                 unsigned short* __restrict__ lo, int n) {
  int stride = gridDim.x * blockDim.x;
  for (int i = blockIdx.x * blockDim.x + threadIdx.x; i * 4 < n; i += stride) {
    int j = i * 4;
    float4 v = *(const float4*)(src + j);
    ushort4 h, l;
    h.x = f2h(v.x); l.x = f2h(v.x - h2f(h.x));
    h.y = f2h(v.y); l.y = f2h(v.y - h2f(h.y));
    h.z = f2h(v.z); l.z = f2h(v.z - h2f(h.z));
    h.w = f2h(v.w); l.w = f2h(v.w - h2f(h.w));
    *(ushort4*)(hi + j) = h;
    *(ushort4*)(lo + j) = l;
  }
}

// f32 -> bf16 cast (V path stays bf16)
__global__ __launch_bounds__(256) void k_cast(const float* __restrict__ src,
                                              unsigned short* __restrict__ dst, int n) {
  int stride = gridDim.x * blockDim.x;
  for (int i = blockIdx.x * blockDim.x + threadIdx.x; i * 4 < n; i += stride) {
    int j = i * 4;
    float4 v = *(const float4*)(src + j);
    ushort4 h;
    h.x = f2bf(v.x); h.y = f2bf(v.y); h.z = f2bf(v.z); h.w = f2bf(v.w);
    *(ushort4*)(dst + j) = h;
  }
}

__global__ __launch_bounds__(256) void k_bias2(const float* __restrict__ a,
                                               const float* __restrict__ b,
                                               float* __restrict__ dst) {
  int t = threadIdx.x + blockIdx.x * 256;
  if (t < Cn) { dst[t] = a[t]; dst[Cn + t] = b[t]; }
}

// ---------------------------------------------------------------------------
// 8-phase 256x256 fp16 2-term GEMM (round-6 structure: T1 chunked decode +
// T2 involution swizzle + counted vmcnt(4), 0 bank conflicts, 235us@NT48).
// Virtual K = 2*1024: seg0 = A-hi x B-hi, seg1 = A-hi x B-lo (A-lo dropped).
// MODE 0: merged QK-projection (virtual M=32768; side=tM>=Mn selects Wk).
//         q rows -> flat fp16 into O0 (d_out); k rows -> hi O1 / lo O2.
// MODE 1: QK^T per batch (batch = XCD chunk); fp32 scores (NO 1/sqrt(d)).
// ---------------------------------------------------------------------------
template <int MODE>
__global__ __launch_bounds__(512, 2) void gemm8(
    const unsigned short* __restrict__ Ah,
    const unsigned short* __restrict__ Bh, const unsigned short* __restrict__ Bl,
    const float* __restrict__ bias,
    unsigned short* __restrict__ O0, unsigned short* __restrict__ O1,
    unsigned short* __restrict__ O2, float* __restrict__ Sout) {
  __shared__ unsigned short lds[65536];  // 8 regions x 16 KiB

  const int bid = blockIdx.x;
  const int chunk = bid & 7;   // XCD id (round-robin dispatch)
  const int r = bid >> 3;

  int tM, tN, side = 0, zdec = 0;
  const unsigned short *a0, *b0, *b1;
  if constexpr (MODE == 0) {
    int y = chunk * 16 + (r >> 2);    // XCD-contiguous rows: A ~1x fetch
    int x = r & 3;
    tM = y * 256; tN = x * 256;
    side = (y >= 64);
    a0 = Ah;
    b0 = Bh + side * 1048576; b1 = Bl + side * 1048576;
  } else {
    zdec = chunk;                      // batch per XCD
    int ys = r >> 5, x = (r >> 2) & 7, y4 = r & 3;
    tM = (ys * 4 + y4) * 256; tN = x * 256;
    a0 = Ah + (long long)zdec * 2097152;
    b0 = Bh + (long long)zdec * 2097152; b1 = Bl + (long long)zdec * 2097152;
  }

  const int tid = threadIdx.x;
  const int l = tid & 63;
  const int w = tid >> 6;
  const int wm = w >> 2, wn = w & 3;   // 2 x 4 wave grid
  const int lr = l & 15;
  const int lk = l >> 4;
  // T2 involution: pre-swizzled global source slot + same XOR on read slot
  const int ssw = ((tid & 3) ^ ((tid >> 3) & 3)) * 8;
  const int rsw = (lk ^ ((lr >> 1) & 3)) * 8;

  // stage one 256x32 region (16 KiB): 2 x global_load_lds(16B) per thread
  auto stg = [&](int region, int tile, int ks, bool isA) {
    int tt = tile < NT ? tile : NT - 1;  // tail clamp keeps vmcnt ledger uniform
    int seg = tt >> 4;
    int k0 = (tt & 15) * 64 + ks * 32;
    const unsigned short* G = isA ? a0 : (seg ? b1 : b0);
    int tb = isA ? tM : tN;
    unsigned short* D = lds + region * 8192;
#pragma unroll
    for (int j = 0; j < 2; ++j)
      stage16(G + (long long)(tb + j * 128 + (tid >> 2)) * 1024 + k0 + ssw,
              D + j * 4096 + (size_t)tid * 8);
  };

  f32x4 acc[8][4] = {};

  // prologue: tile0 (both k-halves) + tile1 k-half0; regions 0,2,1,3 must land
  stg(0, 0, 0, true);  stg(2, 0, 0, false);
  stg(1, 0, 1, true);  stg(3, 0, 1, false);
  stg(4, 1, 0, true);  stg(6, 1, 0, false);
  asm volatile("s_waitcnt vmcnt(4)" ::: "memory");
  __builtin_amdgcn_sched_barrier(0);
  __builtin_amdgcn_s_barrier();

  for (int i = 0; i < NI; ++i) {
    const int e = 2 * i;
#pragma unroll
    for (int p = 0; p < 8; ++p) {
      const int buf = p >> 2, q = p & 3, mh = q & 1, ks = q >> 1;
      const unsigned short* Ar = lds + (buf * 4 + ks) * 8192;
      const unsigned short* Br = lds + (buf * 4 + 2 + ks) * 8192;
      f16x8 av[4], bv[4];
#pragma unroll
      for (int fm = 0; fm < 4; ++fm)
        av[fm] = *(const f16x8*)&Ar[(wm * 128 + mh * 64 + fm * 16 + lr) * 32 + rsw];
#pragma unroll
      for (int fn = 0; fn < 4; ++fn)
        bv[fn] = *(const f16x8*)&Br[(wn * 64 + fn * 16 + lr) * 32 + rsw];
      // stage slots target regions whose reads completed last phase
      if (p == 0)      { stg(5, e + 1, 1, true); stg(7, e + 1, 1, false); }
      else if (p == 2) { stg(0, e + 2, 0, true); stg(2, e + 2, 0, false); }
      else if (p == 4) { stg(1, e + 2, 1, true); stg(3, e + 2, 1, false); }
      else if (p == 6) { stg(4, e + 3, 0, true); stg(6, e + 3, 0, false); }
      __builtin_amdgcn_s_barrier();
      asm volatile("s_waitcnt lgkmcnt(0)" ::: "memory");
      __builtin_amdgcn_sched_barrier(0);
      __builtin_amdgcn_s_setprio(1);
#pragma unroll
      for (int fm = 0; fm < 4; ++fm)
#pragma unroll
        for (int fn = 0; fn < 4; ++fn)
          acc[mh * 4 + fm][fn] = __builtin_amdgcn_mfma_f32_16x16x32_f16(
              av[fm], bv[fn], acc[mh * 4 + fm][fn], 0, 0, 0);
      __builtin_amdgcn_s_setprio(0);
      if (p == 3 || p == 7) {
        asm volatile("s_waitcnt vmcnt(4)" ::: "memory");
        __builtin_amdgcn_sched_barrier(0);
      }
      __builtin_amdgcn_s_barrier();
    }
  }

#pragma unroll
  for (int am = 0; am < 8; ++am)
#pragma unroll
    for (int an = 0; an < 4; ++an)
#pragma unroll
      for (int r2 = 0; r2 < 4; ++r2) {
        int rg = tM + wm * 128 + am * 16 + (l >> 4) * 4 + r2;
        int cg = tN + wn * 64 + an * 16 + lr;
        float v = acc[am][an][r2];
        if constexpr (MODE == 0) {
          v += bias[side * 1024 + cg];
          if (!side) {
            O0[(long long)rg * 1024 + cg] = f2h(v);  // q: flat fp16
          } else {
            long long off = (long long)(rg - Mn) * 1024 + cg;
            unsigned short h = f2h(v);
            O1[off] = h;
            O2[off] = f2h(v - h2f(h));
          }
        } else {
          Sout[(long long)zdec * 4194304ll + (long long)rg * 2048 + cg] = v;
        }
      }
}

// ---------------------------------------------------------------------------
// 2-barrier 128x128 PLAIN bf16 GEMM (V path), linear staging/reads.
// PM 0: Vproj  vT[d][s] = (x3 @ Wv^T + bv)^T, grid (128,8).
// PM 1: PV     out[b] = attn[b] @ v[b], grid (8,16,8) z=batch, K=2048.
// ---------------------------------------------------------------------------
template <int PM>
__global__ __launch_bounds__(256) void gemm2p(
    const unsigned short* __restrict__ A, const unsigned short* __restrict__ B,
    const float* __restrict__ bias, unsigned short* __restrict__ Obf,
    float* __restrict__ Of) {
  __shared__ unsigned short smem[8192];
  unsigned short* As = smem;
  unsigned short* Bs = smem + 4096;

  int tM, tN, z = 0;
  const unsigned short *ap, *bp;
  int lda, ldb;
  tN = blockIdx.x * 128;
  tM = blockIdx.y * 128;
  if constexpr (PM == 0) {
    ap = A; bp = B; lda = 1024; ldb = 1024;
  } else {
    z = blockIdx.z;
    ap = A + (long long)z * 8388608;  // attn batch (fp32-row region, shorts)
    bp = B + (long long)z * 2048;     // vT column slice
    lda = 4096; ldb = 16384;
  }
  constexpr int K = (PM == 0) ? 1024 : 2048;

  const int t = threadIdx.x;
  const int l = t & 63;
  const int w = t >> 6;
  const int wr = w >> 1, wc = w & 1;
  const int lr = l & 15;
  const int lk = (l >> 4) * 8;

  f32x4 acc[4][4] = {};

  for (int k0 = 0; k0 < K; k0 += 32) {
#pragma unroll
    for (int c = 0; c < 2; ++c) {
      int idx = c * 256 + t;
      int row = idx >> 2;
      int co = (idx & 3) * 8;
      stage16(ap + (long long)(tM + row) * lda + k0 + co, As + idx * 8);
      stage16(bp + (long long)(tN + row) * ldb + k0 + co, Bs + idx * 8);
    }
    __syncthreads();
    typedef __bf16 bf16x8 __attribute__((ext_vector_type(8)));
    bf16x8 av[4], bv[4];
#pragma unroll
    for (int i = 0; i < 4; ++i) {
      av[i] = *(const bf16x8*)&As[(wr * 64 + i * 16 + lr) * 32 + lk];
      bv[i] = *(const bf16x8*)&Bs[(wc * 64 + i * 16 + lr) * 32 + lk];
    }
#pragma unroll
    for (int mi = 0; mi < 4; ++mi)
#pragma unroll
      for (int ni = 0; ni < 4; ++ni)
        acc[mi][ni] = __builtin_amdgcn_mfma_f32_16x16x32_bf16(av[mi], bv[ni], acc[mi][ni], 0, 0, 0);
    __syncthreads();
  }

#pragma unroll
  for (int mi = 0; mi < 4; ++mi)
#pragma unroll
    for (int ni = 0; ni < 4; ++ni)
#pragma unroll
      for (int r2 = 0; r2 < 4; ++r2) {
        int rg = tM + wr * 64 + mi * 16 + (l >> 4) * 4 + r2;
        int cg = tN + wc * 64 + ni * 16 + lr;
        float v = acc[mi][ni][r2];
        if constexpr (PM == 0) {
          v += bias[rg];
          Obf[(long long)rg * 16384 + cg] = f2bf(v);
        } else {
          Of[(long long)z * 2097152ll + (long long)rg * 1024 + cg] = v;
        }
      }
}

// In-place row softmax: fp32 row [Sn] -> normalized bf16 attn in first Sn shorts.
__global__ __launch_bounds__(256) void k_softmax(float* __restrict__ S) {
  const long long row = blockIdx.x;
  float* src = S + row * Sn;
  const int t = threadIdx.x;
  float4 v0 = *(const float4*)(src + t * 8);
  float4 v1 = *(const float4*)(src + t * 8 + 4);
  float m = fmaxf(fmaxf(fmaxf(v0.x, v0.y), fmaxf(v0.z, v0.w)),
                  fmaxf(fmaxf(v1.x, v1.y), fmaxf(v1.z, v1.w)));
#pragma unroll
  for (int off = 32; off > 0; off >>= 1) m = fmaxf(m, __shfl_xor(m, off));
  __shared__ float red[8];
  if ((t & 63) == 0) red[t >> 6] = m;
  __syncthreads();
  m = fmaxf(fmaxf(red[0], red[1]), fmaxf(red[2], red[3]));
  float e[8];
  e[0] = __expf(v0.x - m); e[1] = __expf(v0.y - m);
  e[2] = __expf(v0.z - m); e[3] = __expf(v0.w - m);
  e[4] = __expf(v1.x - m); e[5] = __expf(v1.y - m);
  e[6] = __expf(v1.z - m); e[7] = __expf(v1.w - m);
  float s = ((e[0] + e[1]) + (e[2] + e[3])) + ((e[4] + e[5]) + (e[6] + e[7]));
#pragma unroll
  for (int off = 32; off > 0; off >>= 1) s += __shfl_xor(s, off);
  if ((t & 63) == 0) red[4 + (t >> 6)] = s;
  __syncthreads();
  s = (red[4] + red[5]) + (red[6] + red[7]);
  float inv = 1.0f / s;
  us8 o;
#pragma unroll
  for (int j = 0; j < 8; ++j) o[j] = f2bf(e[j] * inv);
  *(us8*)((unsigned short*)src + t * 8) = o;
}

}  // namespace

extern "C" void kernel_launch(void* const* d_in, const int* in_sizes, int n_in,
                              void* d_out, int out_size, void* d_ws, size_t ws_size,
                              hipStream_t stream) {
  (void)in_sizes; (void)n_in; (void)out_size;
  const float* x1 = (const float*)d_in[0];
  const float* x2 = (const float*)d_in[1];
  const float* x3 = (const float*)d_in[2];
  const float* Wq = (const float*)d_in[3];
  const float* bq = (const float*)d_in[4];
  const float* Wk = (const float*)d_in[5];
  const float* bk = (const float*)d_in[6];
  const float* Wv = (const float*)d_in[7];
  const float* bv = (const float*)d_in[8];
  float* out = (float*)d_out;
  char* ws = (char*)d_ws;

  const size_t MiB = 1048576ull;
  // ws layout (MiB): [0,4) W-hi fp16 (Wq|Wk) [4,8) W-lo [8,9) bias_cat
  // [9,11) wvb(bf16) [12,44) kh [44,76) kl [76,108) vT
  // [108,140) x3b(bf16, pre-Vproj) -> x1h(fp16) [140,172) x2h(fp16)
  // S fp32 [108,236) overlays x1h/x2h (dead after QK-proj). NEED 236 (<266).
  unsigned short* wqh = (unsigned short*)(ws);
  unsigned short* wql = (unsigned short*)(ws + 4 * MiB);
  float* bias_cat = (float*)(ws + 8 * MiB);
  unsigned short* wvb = (unsigned short*)(ws + 9 * MiB);
  unsigned short* kh  = (unsigned short*)(ws + 12 * MiB);
  unsigned short* kl  = (unsigned short*)(ws + 44 * MiB);
  unsigned short* vT  = (unsigned short*)(ws + 76 * MiB);
  unsigned short* x3b = (unsigned short*)(ws + 108 * MiB);
  unsigned short* x1h = (unsigned short*)(ws + 108 * MiB);
  unsigned short* x2h = (unsigned short*)(ws + 140 * MiB);
  float* S = (float*)(ws + 108 * MiB);
  if (ws_size < 236 * MiB) return;  // visible failure => ws probe

  unsigned short* qh = (unsigned short*)d_out;  // q flat fp16, batch stride 2M shorts

  const int nx = Mn * Cn, nw = Cn * Cn;
  // 1) V path first (x3b overlays the future x1h region).
  k_cast<<<2048, 256, 0, stream>>>(x3, x3b, nx);
  k_cast<<<256, 256, 0, stream>>>(Wv, wvb, nw);
  {
    dim3 gv(128, 8, 1);
    gemm2p<0><<<gv, 256, 0, stream>>>(wvb, x3b, bv, vT, nullptr);
  }
  // 2) fp16 prep: x casts (no lo needed — A-side lo term dropped), W splits.
  k_cast16<<<2048, 256, 0, stream>>>(x1, x1h, nx);
  k_cast16<<<2048, 256, 0, stream>>>(x2, x2h, nx);
  k_split16<<<256, 256, 0, stream>>>(Wq, wqh, wql, nw);
  k_split16<<<256, 256, 0, stream>>>(Wk, wqh + 1048576, wql + 1048576, nw);
  k_bias2<<<4, 256, 0, stream>>>(bq, bk, bias_cat);
  // 3) merged Q+K projection, 8-phase 256^2, fp16 2-term (virtual M=32768).
  gemm8<0><<<512, 512, 0, stream>>>(x1h, wqh, wql, bias_cat, qh, kh, kl, nullptr);
  // 4) scores = q @ k^T per batch, fp16 2-term (NO 1/sqrt(d)).
  gemm8<1><<<512, 512, 0, stream>>>(qh, kh, kl, nullptr, nullptr, nullptr, nullptr, S);
  // 5) in-place softmax -> bf16 attn rows.
  k_softmax<<<Mn, 256, 0, stream>>>(S);
  // 6) out[b] = attn[b] @ v[b].
  {
    dim3 gp(8, 16, 8);
    gemm2p<1><<<gp, 256, 0, stream>>>((unsigned short*)S, vT, nullptr, nullptr, out);
  }
}

// Round 11
// 433.276 us; speedup vs baseline: 1.7799x; 1.3000x over previous
//
#include <hip/hip_runtime.h>
#include <stdint.h>

namespace {

constexpr int Bn = 8;
constexpr int Sn = 2048;
constexpr int Cn = 1024;
constexpr int Mn = Bn * Sn;  // 16384
constexpr int NT = 16;       // K-tiles of BK=64 (K=1024, plain single-term)
constexpr int NI = NT / 2;

typedef float f32x4 __attribute__((ext_vector_type(4)));
typedef _Float16 f16x8 __attribute__((ext_vector_type(8)));
typedef unsigned short us8 __attribute__((ext_vector_type(8)));

__device__ __forceinline__ unsigned short f2h(float f) {
  _Float16 h = (_Float16)f;
  unsigned short u;
  __builtin_memcpy(&u, &h, 2);
  return u;
}

__device__ __forceinline__ void stage16(const unsigned short* g, unsigned short* l) {
  __builtin_amdgcn_global_load_lds(
      (const __attribute__((address_space(1))) void*)g,
      (__attribute__((address_space(3))) void*)l, 16, 0, 0);
}

// f32 -> fp16 cast, vectorized
__global__ __launch_bounds__(256) void k_cast16(const float* __restrict__ src,
                                                unsigned short* __restrict__ dst, int n) {
  int stride = gridDim.x * blockDim.x;
  for (int i = blockIdx.x * blockDim.x + threadIdx.x; i * 4 < n; i += stride) {
    int j = i * 4;
    float4 v = *(const float4*)(src + j);
    ushort4 h;
    h.x = f2h(v.x); h.y = f2h(v.y); h.z = f2h(v.z); h.w = f2h(v.w);
    *(ushort4*)(dst + j) = h;
  }
}

__global__ __launch_bounds__(256) void k_bias2(const float* __restrict__ a,
                                               const float* __restrict__ b,
                                               float* __restrict__ dst) {
  int t = threadIdx.x + blockIdx.x * 256;
  if (t < Cn) { dst[t] = a[t]; dst[Cn + t] = b[t]; }
}

// ---------------------------------------------------------------------------
// 8-phase 256x256 plain-fp16 GEMM (round-6 structure: T1 chunked decode +
// T2 involution swizzle + counted vmcnt(4); 0 bank conflicts; proven ladder
// 253->235->160us at NT 48/48/32 — now NT=16, K=1024 single-term).
// MODE 0: merged QK-projection (virtual M=32768; side=tM>=Mn selects Wk).
//         q rows -> flat fp16 into O0 (d_out); k rows -> fp16 O1.
// MODE 1: QK^T per batch (batch = XCD chunk); fp32 scores (NO 1/sqrt(d)).
// ---------------------------------------------------------------------------
template <int MODE>
__global__ __launch_bounds__(512, 2) void gemm8(
    const unsigned short* __restrict__ Ah, const unsigned short* __restrict__ Bh,
    const float* __restrict__ bias,
    unsigned short* __restrict__ O0, unsigned short* __restrict__ O1,
    float* __restrict__ Sout) {
  __shared__ unsigned short lds[65536];  // 8 regions x 16 KiB

  const int bid = blockIdx.x;
  const int chunk = bid & 7;   // XCD id (round-robin dispatch)
  const int r = bid >> 3;

  int tM, tN, side = 0, zdec = 0;
  const unsigned short *a0, *b0;
  if constexpr (MODE == 0) {
    int y = chunk * 16 + (r >> 2);    // XCD-contiguous rows: A ~1x fetch
    int x = r & 3;
    tM = y * 256; tN = x * 256;
    side = (y >= 64);
    a0 = Ah;
    b0 = Bh + side * 1048576;
  } else {
    zdec = chunk;                      // batch per XCD
    int ys = r >> 5, x = (r >> 2) & 7, y4 = r & 3;
    tM = (ys * 4 + y4) * 256; tN = x * 256;
    a0 = Ah + (long long)zdec * 2097152;
    b0 = Bh + (long long)zdec * 2097152;
  }

  const int tid = threadIdx.x;
  const int l = tid & 63;
  const int w = tid >> 6;
  const int wm = w >> 2, wn = w & 3;   // 2 x 4 wave grid
  const int lr = l & 15;
  const int lk = l >> 4;
  // T2 involution: pre-swizzled global source slot + same XOR on read slot
  const int ssw = ((tid & 3) ^ ((tid >> 3) & 3)) * 8;
  const int rsw = (lk ^ ((lr >> 1) & 3)) * 8;

  // stage one 256x32 region (16 KiB): 2 x global_load_lds(16B) per thread
  auto stg = [&](int region, int tile, int ks, bool isA) {
    int tt = tile < NT ? tile : NT - 1;  // tail clamp keeps vmcnt ledger uniform
    int k0 = tt * 64 + ks * 32;
    const unsigned short* G = isA ? a0 : b0;
    int tb = isA ? tM : tN;
    unsigned short* D = lds + region * 8192;
#pragma unroll
    for (int j = 0; j < 2; ++j)
      stage16(G + (long long)(tb + j * 128 + (tid >> 2)) * 1024 + k0 + ssw,
              D + j * 4096 + (size_t)tid * 8);
  };

  f32x4 acc[8][4] = {};

  // prologue: tile0 (both k-halves) + tile1 k-half0; regions 0,2,1,3 must land
  stg(0, 0, 0, true);  stg(2, 0, 0, false);
  stg(1, 0, 1, true);  stg(3, 0, 1, false);
  stg(4, 1, 0, true);  stg(6, 1, 0, false);
  asm volatile("s_waitcnt vmcnt(4)" ::: "memory");
  __builtin_amdgcn_sched_barrier(0);
  __builtin_amdgcn_s_barrier();

  for (int i = 0; i < NI; ++i) {
    const int e = 2 * i;
#pragma unroll
    for (int p = 0; p < 8; ++p) {
      const int buf = p >> 2, q = p & 3, mh = q & 1, ks = q >> 1;
      const unsigned short* Ar = lds + (buf * 4 + ks) * 8192;
      const unsigned short* Br = lds + (buf * 4 + 2 + ks) * 8192;
      f16x8 av[4], bv[4];
#pragma unroll
      for (int fm = 0; fm < 4; ++fm)
        av[fm] = *(const f16x8*)&Ar[(wm * 128 + mh * 64 + fm * 16 + lr) * 32 + rsw];
#pragma unroll
      for (int fn = 0; fn < 4; ++fn)
        bv[fn] = *(const f16x8*)&Br[(wn * 64 + fn * 16 + lr) * 32 + rsw];
      // stage slots target regions whose reads completed last phase
      if (p == 0)      { stg(5, e + 1, 1, true); stg(7, e + 1, 1, false); }
      else if (p == 2) { stg(0, e + 2, 0, true); stg(2, e + 2, 0, false); }
      else if (p == 4) { stg(1, e + 2, 1, true); stg(3, e + 2, 1, false); }
      else if (p == 6) { stg(4, e + 3, 0, true); stg(6, e + 3, 0, false); }
      __builtin_amdgcn_s_barrier();
      asm volatile("s_waitcnt lgkmcnt(0)" ::: "memory");
      __builtin_amdgcn_sched_barrier(0);
      __builtin_amdgcn_s_setprio(1);
#pragma unroll
      for (int fm = 0; fm < 4; ++fm)
#pragma unroll
        for (int fn = 0; fn < 4; ++fn)
          acc[mh * 4 + fm][fn] = __builtin_amdgcn_mfma_f32_16x16x32_f16(
              av[fm], bv[fn], acc[mh * 4 + fm][fn], 0, 0, 0);
      __builtin_amdgcn_s_setprio(0);
      if (p == 3 || p == 7) {
        asm volatile("s_waitcnt vmcnt(4)" ::: "memory");
        __builtin_amdgcn_sched_barrier(0);
      }
      __builtin_amdgcn_s_barrier();
    }
  }

#pragma unroll
  for (int am = 0; am < 8; ++am)
#pragma unroll
    for (int an = 0; an < 4; ++an)
#pragma unroll
      for (int r2 = 0; r2 < 4; ++r2) {
        int rg = tM + wm * 128 + am * 16 + (l >> 4) * 4 + r2;
        int cg = tN + wn * 64 + an * 16 + lr;
        float v = acc[am][an][r2];
        if constexpr (MODE == 0) {
          v += bias[side * 1024 + cg];
          if (!side) {
            O0[(long long)rg * 1024 + cg] = f2h(v);          // q flat fp16
          } else {
            O1[(long long)(rg - Mn) * 1024 + cg] = f2h(v);   // k flat fp16
          }
        } else {
          Sout[(long long)zdec * 4194304ll + (long long)rg * 2048 + cg] = v;
        }
      }
}

// ---------------------------------------------------------------------------
// 2-barrier 128x128 plain fp16 GEMM (V path), linear staging/reads.
// PM 0: Vproj  vT[d][s] = (x3 @ Wv^T + bv)^T, grid (128,8), fp16 out.
// PM 1: PV     out[b] = attn[b] @ v[b], grid (8,16,8) z=batch, K=2048, f32 out.
// ---------------------------------------------------------------------------
template <int PM>
__global__ __launch_bounds__(256) void gemm2p(
    const unsigned short* __restrict__ A, const unsigned short* __restrict__ B,
    const float* __restrict__ bias, unsigned short* __restrict__ Oh,
    float* __restrict__ Of) {
  __shared__ unsigned short smem[8192];
  unsigned short* As = smem;
  unsigned short* Bs = smem + 4096;

  int tM, tN, z = 0;
  const unsigned short *ap, *bp;
  int lda, ldb;
  tN = blockIdx.x * 128;
  tM = blockIdx.y * 128;
  if constexpr (PM == 0) {
    ap = A; bp = B; lda = 1024; ldb = 1024;
  } else {
    z = blockIdx.z;
    ap = A + (long long)z * 8388608;  // attn batch (fp32-row region, shorts)
    bp = B + (long long)z * 2048;     // vT column slice
    lda = 4096; ldb = 16384;
  }
  constexpr int K = (PM == 0) ? 1024 : 2048;

  const int t = threadIdx.x;
  const int l = t & 63;
  const int w = t >> 6;
  const int wr = w >> 1, wc = w & 1;
  const int lr = l & 15;
  const int lk = (l >> 4) * 8;

  f32x4 acc[4][4] = {};

  for (int k0 = 0; k0 < K; k0 += 32) {
#pragma unroll
    for (int c = 0; c < 2; ++c) {
      int idx = c * 256 + t;
      int row = idx >> 2;
      int co = (idx & 3) * 8;
      stage16(ap + (long long)(tM + row) * lda + k0 + co, As + idx * 8);
      stage16(bp + (long long)(tN + row) * ldb + k0 + co, Bs + idx * 8);
    }
    __syncthreads();
    f16x8 av[4], bv[4];
#pragma unroll
    for (int i = 0; i < 4; ++i) {
      av[i] = *(const f16x8*)&As[(wr * 64 + i * 16 + lr) * 32 + lk];
      bv[i] = *(const f16x8*)&Bs[(wc * 64 + i * 16 + lr) * 32 + lk];
    }
#pragma unroll
    for (int mi = 0; mi < 4; ++mi)
#pragma unroll
      for (int ni = 0; ni < 4; ++ni)
        acc[mi][ni] = __builtin_amdgcn_mfma_f32_16x16x32_f16(av[mi], bv[ni], acc[mi][ni], 0, 0, 0);
    __syncthreads();
  }

#pragma unroll
  for (int mi = 0; mi < 4; ++mi)
#pragma unroll
    for (int ni = 0; ni < 4; ++ni)
#pragma unroll
      for (int r2 = 0; r2 < 4; ++r2) {
        int rg = tM + wr * 64 + mi * 16 + (l >> 4) * 4 + r2;
        int cg = tN + wc * 64 + ni * 16 + lr;
        float v = acc[mi][ni][r2];
        if constexpr (PM == 0) {
          v += bias[rg];
          Oh[(long long)rg * 16384 + cg] = f2h(v);
        } else {
          Of[(long long)z * 2097152ll + (long long)rg * 1024 + cg] = v;
        }
      }
}

// In-place row softmax: fp32 row [Sn] -> normalized fp16 attn in first Sn shorts.
// Reads complete before first barrier, writes after the second -> race-free.
__global__ __launch_bounds__(256) void k_softmax(float* __restrict__ S) {
  const long long row = blockIdx.x;
  float* src = S + row * Sn;
  const int t = threadIdx.x;
  float4 v0 = *(const float4*)(src + t * 8);
  float4 v1 = *(const float4*)(src + t * 8 + 4);
  float m = fmaxf(fmaxf(fmaxf(v0.x, v0.y), fmaxf(v0.z, v0.w)),
                  fmaxf(fmaxf(v1.x, v1.y), fmaxf(v1.z, v1.w)));
#pragma unroll
  for (int off = 32; off > 0; off >>= 1) m = fmaxf(m, __shfl_xor(m, off));
  __shared__ float red[8];
  if ((t & 63) == 0) red[t >> 6] = m;
  __syncthreads();
  m = fmaxf(fmaxf(red[0], red[1]), fmaxf(red[2], red[3]));
  float e[8];
  e[0] = __expf(v0.x - m); e[1] = __expf(v0.y - m);
  e[2] = __expf(v0.z - m); e[3] = __expf(v0.w - m);
  e[4] = __expf(v1.x - m); e[5] = __expf(v1.y - m);
  e[6] = __expf(v1.z - m); e[7] = __expf(v1.w - m);
  float s = ((e[0] + e[1]) + (e[2] + e[3])) + ((e[4] + e[5]) + (e[6] + e[7]));
#pragma unroll
  for (int off = 32; off > 0; off >>= 1) s += __shfl_xor(s, off);
  if ((t & 63) == 0) red[4 + (t >> 6)] = s;
  __syncthreads();
  s = (red[4] + red[5]) + (red[6] + red[7]);
  float inv = 1.0f / s;
  us8 o;
#pragma unroll
  for (int j = 0; j < 8; ++j) o[j] = f2h(e[j] * inv);
  *(us8*)((unsigned short*)src + t * 8) = o;
}

}  // namespace

extern "C" void kernel_launch(void* const* d_in, const int* in_sizes, int n_in,
                              void* d_out, int out_size, void* d_ws, size_t ws_size,
                              hipStream_t stream) {
  (void)in_sizes; (void)n_in; (void)out_size;
  const float* x1 = (const float*)d_in[0];
  const float* x2 = (const float*)d_in[1];
  const float* x3 = (const float*)d_in[2];
  const float* Wq = (const float*)d_in[3];
  const float* bq = (const float*)d_in[4];
  const float* Wk = (const float*)d_in[5];
  const float* bk = (const float*)d_in[6];
  const float* Wv = (const float*)d_in[7];
  const float* bv = (const float*)d_in[8];
  float* out = (float*)d_out;
  char* ws = (char*)d_ws;

  const size_t MiB = 1048576ull;
  // ws layout (MiB): [0,2) Wq fp16 [2,4) Wk fp16 [4,5) bias_cat [5,7) Wv fp16
  // [12,44) kh fp16 [44,76) vT fp16
  // [76,108) x3h (pre-Vproj) -> x1h ; [108,140) x2h
  // S fp32 [76,204) overlays x1h/x2h (dead after QK-proj). NEED 204 (<266 proven).
  unsigned short* wqk = (unsigned short*)(ws);         // Wq | Wk (1M shorts each)
  float* bias_cat = (float*)(ws + 4 * MiB);
  unsigned short* wvh = (unsigned short*)(ws + 5 * MiB);
  unsigned short* kh  = (unsigned short*)(ws + 12 * MiB);
  unsigned short* vT  = (unsigned short*)(ws + 44 * MiB);
  unsigned short* x3h = (unsigned short*)(ws + 76 * MiB);
  unsigned short* x1h = (unsigned short*)(ws + 76 * MiB);
  unsigned short* x2h = (unsigned short*)(ws + 108 * MiB);
  float* S = (float*)(ws + 76 * MiB);
  if (ws_size < 204 * MiB) return;  // visible failure => ws probe

  unsigned short* qh = (unsigned short*)d_out;  // q flat fp16, batch stride 2M shorts

  const int nx = Mn * Cn, nw = Cn * Cn;
  // 1) V path first (x3h overlays the future x1h region).
  k_cast16<<<2048, 256, 0, stream>>>(x3, x3h, nx);
  k_cast16<<<256, 256, 0, stream>>>(Wv, wvh, nw);
  {
    dim3 gv(128, 8, 1);
    gemm2p<0><<<gv, 256, 0, stream>>>(wvh, x3h, bv, vT, nullptr);
  }
  // 2) fp16 prep (plain single-term: casts only, no splits).
  k_cast16<<<2048, 256, 0, stream>>>(x1, x1h, nx);
  k_cast16<<<2048, 256, 0, stream>>>(x2, x2h, nx);
  k_cast16<<<256, 256, 0, stream>>>(Wq, wqk, nw);
  k_cast16<<<256, 256, 0, stream>>>(Wk, wqk + 1048576, nw);
  k_bias2<<<4, 256, 0, stream>>>(bq, bk, bias_cat);
  // 3) merged Q+K projection, 8-phase 256^2, plain fp16 (virtual M=32768).
  gemm8<0><<<512, 512, 0, stream>>>(x1h, wqk, bias_cat, qh, kh, nullptr);
  // 4) scores = q @ k^T per batch, plain fp16 (NO 1/sqrt(d)).
  gemm8<1><<<512, 512, 0, stream>>>(qh, kh, nullptr, nullptr, nullptr, S);
  // 5) in-place softmax -> fp16 attn rows.
  k_softmax<<<Mn, 256, 0, stream>>>(S);
  // 6) out[b] = attn[b] @ v[b] (fp16 attn x fp16 vT, fp32 out).
  {
    dim3 gp(8, 16, 8);
    gemm2p<1><<<gp, 256, 0, stream>>>((unsigned short*)S, vT, nullptr, nullptr, out);
  }
}

// Round 12
// 369.355 us; speedup vs baseline: 2.0879x; 1.1731x over previous
//
#include <hip/hip_runtime.h>
#include <stdint.h>

namespace {

constexpr int Bn = 8;
constexpr int Sn = 2048;
constexpr int Cn = 1024;
constexpr int Mn = Bn * Sn;  // 16384

typedef float f32x4 __attribute__((ext_vector_type(4)));
typedef _Float16 f16x8 __attribute__((ext_vector_type(8)));
typedef unsigned short us8 __attribute__((ext_vector_type(8)));

__device__ __forceinline__ unsigned short f2h(float f) {
  _Float16 h = (_Float16)f;
  unsigned short u;
  __builtin_memcpy(&u, &h, 2);
  return u;
}

__device__ __forceinline__ void stage16(const unsigned short* g, unsigned short* l) {
  __builtin_amdgcn_global_load_lds(
      (const __attribute__((address_space(1))) void*)g,
      (__attribute__((address_space(3))) void*)l, 16, 0, 0);
}

// f32 -> fp16 cast, vectorized
__global__ __launch_bounds__(256) void k_cast16(const float* __restrict__ src,
                                                unsigned short* __restrict__ dst, int n) {
  int stride = gridDim.x * blockDim.x;
  for (int i = blockIdx.x * blockDim.x + threadIdx.x; i * 4 < n; i += stride) {
    int j = i * 4;
    float4 v = *(const float4*)(src + j);
    ushort4 h;
    h.x = f2h(v.x); h.y = f2h(v.y); h.z = f2h(v.z); h.w = f2h(v.w);
    *(ushort4*)(dst + j) = h;
  }
}

__global__ __launch_bounds__(256) void k_bias2(const float* __restrict__ a,
                                               const float* __restrict__ b,
                                               float* __restrict__ dst) {
  int t = threadIdx.x + blockIdx.x * 256;
  if (t < Cn) { dst[t] = a[t]; dst[Cn + t] = b[t]; }
}

// ---------------------------------------------------------------------------
// 8-phase 256x256 plain-fp16 GEMM — unified for all four GEMMs.
// Structure (proven r6/r10/r11): T1 XCD-chunked decode + T2 involution
// swizzle (0 bank conflicts) + counted vmcnt(4) at phases 3/7 + setprio.
// MODE 0: merged QK-projection, 512 blocks. Virtual M=32768; side=tM>=Mn
//         selects Wk. q rows -> flat fp16 O0 (d_out); k rows -> fp16 O1.
// MODE 1: QK^T per batch (batch=XCD), 512 blocks; fp32 scores (NO 1/sqrt d).
// MODE 2: PV per batch (batch=XCD), 256 blocks. A=attn (lda 4096, batch
//         stride 8M shorts), B=vT (ldb 16384, batch col offs), K=2048,
//         fp32 out -> Of (d_out).
// MODE 3: Vproj, 256 blocks, N-chunked per XCD. A=Wv, B=x3h, row bias,
//         fp16 out vT (ldc 16384).
// ---------------------------------------------------------------------------
template <int MODE>
__global__ __launch_bounds__(512, 2) void gemm8(
    const unsigned short* __restrict__ Ah, const unsigned short* __restrict__ Bh,
    const float* __restrict__ bias,
    unsigned short* __restrict__ O0, unsigned short* __restrict__ O1,
    float* __restrict__ Sout, float* __restrict__ Of) {
  __shared__ unsigned short lds[65536];  // 8 regions x 16 KiB

  constexpr int KT = (MODE == 2) ? 32 : 16;  // K-tiles of 64
  constexpr int NIk = KT / 2;

  const int bid = blockIdx.x;
  const int chunk = bid & 7;   // XCD id (round-robin dispatch)
  const int r = bid >> 3;

  int tM, tN, side = 0, zdec = 0, lda, ldb;
  const unsigned short *a0, *b0;
  if constexpr (MODE == 0) {
    int y = chunk * 16 + (r >> 2);    // XCD-contiguous rows: A ~1x fetch
    int x = r & 3;
    tM = y * 256; tN = x * 256;
    side = (y >= 64);
    a0 = Ah; b0 = Bh + side * 1048576;
    lda = 1024; ldb = 1024;
  } else if constexpr (MODE == 1) {
    zdec = chunk;                      // batch per XCD
    int ys = r >> 5, x = (r >> 2) & 7, y4 = r & 3;
    tM = (ys * 4 + y4) * 256; tN = x * 256;
    a0 = Ah + (long long)zdec * 2097152;
    b0 = Bh + (long long)zdec * 2097152;
    lda = 1024; ldb = 1024;
  } else if constexpr (MODE == 2) {
    zdec = chunk;                      // batch per XCD
    int y = r >> 2, x = r & 3;         // 8 M-tiles x 4 N-tiles
    tM = y * 256; tN = x * 256;
    a0 = Ah + (long long)zdec * 8388608;  // attn batch (16 MiB fp32-row region)
    b0 = Bh + (long long)zdec * 2048;     // vT column slice
    lda = 4096; ldb = 16384;
  } else {
    int x = chunk * 8 + (r >> 2);      // XCD-contiguous B cols (x3 panels)
    int y = r & 3;
    tN = x * 256; tM = y * 256;
    a0 = Ah; b0 = Bh;
    lda = 1024; ldb = 1024;
  }

  const int tid = threadIdx.x;
  const int l = tid & 63;
  const int w = tid >> 6;
  const int wm = w >> 2, wn = w & 3;   // 2 x 4 wave grid
  const int lr = l & 15;
  const int lk = l >> 4;
  // T2 involution: pre-swizzled global source slot + same XOR on read slot
  const int ssw = ((tid & 3) ^ ((tid >> 3) & 3)) * 8;
  const int rsw = (lk ^ ((lr >> 1) & 3)) * 8;

  // stage one 256x32 region (16 KiB): 2 x global_load_lds(16B) per thread
  auto stg = [&](int region, int tile, int ks, bool isA) {
    int tt = tile < KT ? tile : KT - 1;  // tail clamp keeps vmcnt ledger uniform
    int k0 = tt * 64 + ks * 32;
    const unsigned short* G = isA ? a0 : b0;
    const long long ld = isA ? lda : ldb;
    int tb = isA ? tM : tN;
    unsigned short* D = lds + region * 8192;
#pragma unroll
    for (int j = 0; j < 2; ++j)
      stage16(G + (long long)(tb + j * 128 + (tid >> 2)) * ld + k0 + ssw,
              D + j * 4096 + (size_t)tid * 8);
  };

  f32x4 acc[8][4] = {};

  // prologue: tile0 (both k-halves) + tile1 k-half0; regions 0,2,1,3 must land
  stg(0, 0, 0, true);  stg(2, 0, 0, false);
  stg(1, 0, 1, true);  stg(3, 0, 1, false);
  stg(4, 1, 0, true);  stg(6, 1, 0, false);
  asm volatile("s_waitcnt vmcnt(4)" ::: "memory");
  __builtin_amdgcn_sched_barrier(0);
  __builtin_amdgcn_s_barrier();

  for (int i = 0; i < NIk; ++i) {
    const int e = 2 * i;
#pragma unroll
    for (int p = 0; p < 8; ++p) {
      const int buf = p >> 2, q = p & 3, mh = q & 1, ks = q >> 1;
      const unsigned short* Ar = lds + (buf * 4 + ks) * 8192;
      const unsigned short* Br = lds + (buf * 4 + 2 + ks) * 8192;
      f16x8 av[4], bv[4];
#pragma unroll
      for (int fm = 0; fm < 4; ++fm)
        av[fm] = *(const f16x8*)&Ar[(wm * 128 + mh * 64 + fm * 16 + lr) * 32 + rsw];
#pragma unroll
      for (int fn = 0; fn < 4; ++fn)
        bv[fn] = *(const f16x8*)&Br[(wn * 64 + fn * 16 + lr) * 32 + rsw];
      // stage slots target regions whose reads completed last phase
      if (p == 0)      { stg(5, e + 1, 1, true); stg(7, e + 1, 1, false); }
      else if (p == 2) { stg(0, e + 2, 0, true); stg(2, e + 2, 0, false); }
      else if (p == 4) { stg(1, e + 2, 1, true); stg(3, e + 2, 1, false); }
      else if (p == 6) { stg(4, e + 3, 0, true); stg(6, e + 3, 0, false); }
      __builtin_amdgcn_s_barrier();
      asm volatile("s_waitcnt lgkmcnt(0)" ::: "memory");
      __builtin_amdgcn_sched_barrier(0);
      __builtin_amdgcn_s_setprio(1);
#pragma unroll
      for (int fm = 0; fm < 4; ++fm)
#pragma unroll
        for (int fn = 0; fn < 4; ++fn)
          acc[mh * 4 + fm][fn] = __builtin_amdgcn_mfma_f32_16x16x32_f16(
              av[fm], bv[fn], acc[mh * 4 + fm][fn], 0, 0, 0);
      __builtin_amdgcn_s_setprio(0);
      if (p == 3 || p == 7) {
        asm volatile("s_waitcnt vmcnt(4)" ::: "memory");
        __builtin_amdgcn_sched_barrier(0);
      }
      __builtin_amdgcn_s_barrier();
    }
  }

#pragma unroll
  for (int am = 0; am < 8; ++am)
#pragma unroll
    for (int an = 0; an < 4; ++an)
#pragma unroll
      for (int r2 = 0; r2 < 4; ++r2) {
        int rg = tM + wm * 128 + am * 16 + (l >> 4) * 4 + r2;
        int cg = tN + wn * 64 + an * 16 + lr;
        float v = acc[am][an][r2];
        if constexpr (MODE == 0) {
          v += bias[side * 1024 + cg];
          if (!side) {
            O0[(long long)rg * 1024 + cg] = f2h(v);          // q flat fp16
          } else {
            O1[(long long)(rg - Mn) * 1024 + cg] = f2h(v);   // k flat fp16
          }
        } else if constexpr (MODE == 1) {
          Sout[(long long)zdec * 4194304ll + (long long)rg * 2048 + cg] = v;
        } else if constexpr (MODE == 2) {
          Of[(long long)zdec * 2097152ll + (long long)rg * 1024 + cg] = v;
        } else {
          O0[(long long)rg * 16384 + cg] = f2h(v + bias[rg]);  // vT fp16
        }
      }
}

// In-place row softmax: fp32 row [Sn] -> normalized fp16 attn in first Sn shorts.
// Reads complete before first barrier, writes after the second -> race-free.
__global__ __launch_bounds__(256) void k_softmax(float* __restrict__ S) {
  const long long row = blockIdx.x;
  float* src = S + row * Sn;
  const int t = threadIdx.x;
  float4 v0 = *(const float4*)(src + t * 8);
  float4 v1 = *(const float4*)(src + t * 8 + 4);
  float m = fmaxf(fmaxf(fmaxf(v0.x, v0.y), fmaxf(v0.z, v0.w)),
                  fmaxf(fmaxf(v1.x, v1.y), fmaxf(v1.z, v1.w)));
#pragma unroll
  for (int off = 32; off > 0; off >>= 1) m = fmaxf(m, __shfl_xor(m, off));
  __shared__ float red[8];
  if ((t & 63) == 0) red[t >> 6] = m;
  __syncthreads();
  m = fmaxf(fmaxf(red[0], red[1]), fmaxf(red[2], red[3]));
  float e[8];
  e[0] = __expf(v0.x - m); e[1] = __expf(v0.y - m);
  e[2] = __expf(v0.z - m); e[3] = __expf(v0.w - m);
  e[4] = __expf(v1.x - m); e[5] = __expf(v1.y - m);
  e[6] = __expf(v1.z - m); e[7] = __expf(v1.w - m);
  float s = ((e[0] + e[1]) + (e[2] + e[3])) + ((e[4] + e[5]) + (e[6] + e[7]));
#pragma unroll
  for (int off = 32; off > 0; off >>= 1) s += __shfl_xor(s, off);
  if ((t & 63) == 0) red[4 + (t >> 6)] = s;
  __syncthreads();
  s = (red[4] + red[5]) + (red[6] + red[7]);
  float inv = 1.0f / s;
  us8 o;
#pragma unroll
  for (int j = 0; j < 8; ++j) o[j] = f2h(e[j] * inv);
  *(us8*)((unsigned short*)src + t * 8) = o;
}

}  // namespace

extern "C" void kernel_launch(void* const* d_in, const int* in_sizes, int n_in,
                              void* d_out, int out_size, void* d_ws, size_t ws_size,
                              hipStream_t stream) {
  (void)in_sizes; (void)n_in; (void)out_size;
  const float* x1 = (const float*)d_in[0];
  const float* x2 = (const float*)d_in[1];
  const float* x3 = (const float*)d_in[2];
  const float* Wq = (const float*)d_in[3];
  const float* bq = (const float*)d_in[4];
  const float* Wk = (const float*)d_in[5];
  const float* bk = (const float*)d_in[6];
  const float* Wv = (const float*)d_in[7];
  const float* bv = (const float*)d_in[8];
  float* out = (float*)d_out;
  char* ws = (char*)d_ws;

  const size_t MiB = 1048576ull;
  // ws layout (MiB): [0,2) Wq fp16 [2,4) Wk fp16 [4,5) bias_cat [5,7) Wv fp16
  // [12,44) kh fp16 [44,76) vT fp16
  // [76,108) x3h (pre-Vproj) -> x1h ; [108,140) x2h
  // S fp32 [76,204) overlays x1h/x2h (dead after QK-proj). NEED 204 (<266 proven).
  unsigned short* wqk = (unsigned short*)(ws);         // Wq | Wk (1M shorts each)
  float* bias_cat = (float*)(ws + 4 * MiB);
  unsigned short* wvh = (unsigned short*)(ws + 5 * MiB);
  unsigned short* kh  = (unsigned short*)(ws + 12 * MiB);
  unsigned short* vT  = (unsigned short*)(ws + 44 * MiB);
  unsigned short* x3h = (unsigned short*)(ws + 76 * MiB);
  unsigned short* x1h = (unsigned short*)(ws + 76 * MiB);
  unsigned short* x2h = (unsigned short*)(ws + 108 * MiB);
  float* S = (float*)(ws + 76 * MiB);
  if (ws_size < 204 * MiB) return;  // visible failure => ws probe

  unsigned short* qh = (unsigned short*)d_out;  // q flat fp16

  const int nx = Mn * Cn, nw = Cn * Cn;
  // 1) V path first (x3h overlays the future x1h region).
  k_cast16<<<2048, 256, 0, stream>>>(x3, x3h, nx);
  k_cast16<<<256, 256, 0, stream>>>(Wv, wvh, nw);
  gemm8<3><<<256, 512, 0, stream>>>(wvh, x3h, bv, vT, nullptr, nullptr, nullptr);
  // 2) fp16 prep (plain single-term: casts only).
  k_cast16<<<2048, 256, 0, stream>>>(x1, x1h, nx);
  k_cast16<<<2048, 256, 0, stream>>>(x2, x2h, nx);
  k_cast16<<<256, 256, 0, stream>>>(Wq, wqk, nw);
  k_cast16<<<256, 256, 0, stream>>>(Wk, wqk + 1048576, nw);
  k_bias2<<<4, 256, 0, stream>>>(bq, bk, bias_cat);
  // 3) merged Q+K projection (virtual M=32768).
  gemm8<0><<<512, 512, 0, stream>>>(x1h, wqk, bias_cat, qh, kh, nullptr, nullptr);
  // 4) scores = q @ k^T per batch (NO 1/sqrt(d)).
  gemm8<1><<<512, 512, 0, stream>>>(qh, kh, nullptr, nullptr, nullptr, S, nullptr);
  // 5) in-place softmax -> fp16 attn rows.
  k_softmax<<<Mn, 256, 0, stream>>>(S);
  // 6) out[b] = attn[b] @ v[b] (q in d_out dead after step 4).
  gemm8<2><<<256, 512, 0, stream>>>((unsigned short*)S, vT, nullptr, nullptr,
                                    nullptr, nullptr, out);
}